// Round 1
// baseline (2888.247 us; speedup 1.0000x reference)
//
#include <hip/hip_runtime.h>
#include <math.h>

#define N_NODES   50000
#define N_EDGES   1600000
#define NF        128
#define N_GRAPHS  64
#define N_CLASSES 10

// ---------------------------------------------------------------- zero init
__global__ void k_zero(int* __restrict__ counts, float* __restrict__ sums) {
    int i = blockIdx.x * 256 + threadIdx.x;
    if (i < N_NODES) counts[i] = 0;
    if (i < N_GRAPHS * NF) sums[i] = 0.f;
}

// ---------------------------------------------------------------- in-degree
__global__ void k_count(const int* __restrict__ dst, int* __restrict__ counts) {
    int e = blockIdx.x * 256 + threadIdx.x;
    if (e < N_EDGES) atomicAdd(&counts[dst[e]], 1);
}

// ------------------------------------------------- scan step 1: block sums
__global__ void k_scan_partial(const int* __restrict__ counts, int* __restrict__ bsum) {
    __shared__ int sd[256];
    int b = blockIdx.x, t = threadIdx.x;
    int base = b * 1024 + t * 4;
    int s = 0;
#pragma unroll
    for (int j = 0; j < 4; j++) {
        int idx = base + j;
        if (idx < N_NODES) s += counts[idx];
    }
    sd[t] = s;
    __syncthreads();
    for (int off = 128; off > 0; off >>= 1) {
        if (t < off) sd[t] += sd[t + off];
        __syncthreads();
    }
    if (t == 0) bsum[b] = sd[0];
}

// ------------------------------------- scan step 2: serial scan of 49 sums
__global__ void k_scan_block(const int* __restrict__ bsum, int* __restrict__ boff,
                             int* __restrict__ row_start, int nb) {
    if (threadIdx.x == 0 && blockIdx.x == 0) {
        int run = 0;
        for (int b = 0; b < nb; b++) { boff[b] = run; run += bsum[b]; }
        row_start[N_NODES] = run;
    }
}

// -------------- scan step 3: per-element exclusive scan + node norm factors
__global__ void k_scan_final(const int* __restrict__ counts, const int* __restrict__ boff,
                             int* __restrict__ row_start, int* __restrict__ cursor,
                             float* __restrict__ dis, float* __restrict__ dinv) {
    __shared__ int sd[256];
    int b = blockIdx.x, t = threadIdx.x;
    int base = b * 1024 + t * 4;
    int v[4];
    int s = 0;
#pragma unroll
    for (int j = 0; j < 4; j++) {
        int idx = base + j;
        v[j] = (idx < N_NODES) ? counts[idx] : 0;
        s += v[j];
    }
    sd[t] = s;
    __syncthreads();
    // Hillis-Steele inclusive scan over 256 thread-sums
    for (int off = 1; off < 256; off <<= 1) {
        int y = (t >= off) ? sd[t - off] : 0;
        __syncthreads();
        sd[t] += y;
        __syncthreads();
    }
    int run = sd[t] - s + boff[b];
#pragma unroll
    for (int j = 0; j < 4; j++) {
        int idx = base + j;
        if (idx < N_NODES) {
            row_start[idx] = run;
            cursor[idx] = run;
            float df = (float)(v[j] + 1);  // deg incl. self-loop
            dis[idx]  = rsqrtf(df);
            dinv[idx] = 1.0f / df;
        }
        run += v[j];
    }
}

// ---------------------------------------------------------------- CSR fill
__global__ void k_fill(const int* __restrict__ src, const int* __restrict__ dst,
                       int* __restrict__ cursor, int* __restrict__ csr_src) {
    int e = blockIdx.x * 256 + threadIdx.x;
    if (e < N_EDGES) {
        int d = dst[e];
        int pos = atomicAdd(&cursor[d], 1);
        csr_src[pos] = src[e];
    }
}

// ---------------------------------------------------------------- GEMM
// H[r][c] = sum_k act(X[r][k]) * W[k][c].  64 rows x 128 cols per block,
// thread = 8 rows x 4 cols.  x staged in LDS (pad 132 breaks stride-128
// bank aliasing); w rows read from global (64 KB, L1/L2 resident, shared
// by all blocks).
template <bool ELU>
__global__ __launch_bounds__(256) void k_gemm(const float* __restrict__ X,
                                              const float* __restrict__ W,
                                              float* __restrict__ H) {
    __shared__ float xs[64 * 132];
    int t = threadIdx.x;
    int row0 = blockIdx.x * 64;
#pragma unroll
    for (int i = 0; i < 8; i++) {
        int f = i * 256 + t;          // 0..2047 : 64 rows x 32 float4
        int r = f >> 5, c4 = (f & 31) * 4;
        float4 v = make_float4(0.f, 0.f, 0.f, 0.f);
        if (row0 + r < N_NODES) v = *(const float4*)&X[(size_t)(row0 + r) * NF + c4];
        if (ELU) {
            v.x = v.x > 0.f ? v.x : (expf(v.x) - 1.f);
            v.y = v.y > 0.f ? v.y : (expf(v.y) - 1.f);
            v.z = v.z > 0.f ? v.z : (expf(v.z) - 1.f);
            v.w = v.w > 0.f ? v.w : (expf(v.w) - 1.f);
        }
        *(float4*)&xs[r * 132 + c4] = v;
    }
    __syncthreads();

    int cg = t & 31;   // 4 cols: 4*cg..4*cg+3
    int rg = t >> 5;   // 8 rows: rg*8..rg*8+7
    float acc[8][4] = {};
    for (int k0 = 0; k0 < NF; k0 += 4) {
        float4 xv[8];
#pragma unroll
        for (int rr = 0; rr < 8; rr++)
            xv[rr] = *(const float4*)&xs[(rg * 8 + rr) * 132 + k0];
#pragma unroll
        for (int kk = 0; kk < 4; kk++) {
            float4 wv = *(const float4*)&W[(k0 + kk) * NF + cg * 4];
#pragma unroll
            for (int rr = 0; rr < 8; rr++) {
                float xk = (kk == 0) ? xv[rr].x : (kk == 1) ? xv[rr].y
                         : (kk == 2) ? xv[rr].z : xv[rr].w;
                acc[rr][0] += xk * wv.x;
                acc[rr][1] += xk * wv.y;
                acc[rr][2] += xk * wv.z;
                acc[rr][3] += xk * wv.w;
            }
        }
    }
#pragma unroll
    for (int rr = 0; rr < 8; rr++) {
        int r = row0 + rg * 8 + rr;
        if (r < N_NODES) {
            float4 o = make_float4(acc[rr][0], acc[rr][1], acc[rr][2], acc[rr][3]);
            *(float4*)&H[(size_t)r * NF + cg * 4] = o;
        }
    }
}

// ------------------------------------------------------------- aggregation
// One wave per node; lane holds features 2*lane, 2*lane+1.
// out[i] = dis[i] * sum_e dis[src_e] * H[src_e] + dinv[i]*H[i] + b
__global__ __launch_bounds__(256) void k_agg(const float* __restrict__ H,
                                             const float* __restrict__ bias,
                                             const int* __restrict__ row_start,
                                             const int* __restrict__ csr_src,
                                             const float* __restrict__ dis,
                                             const float* __restrict__ dinv,
                                             float* __restrict__ out) {
    int wid  = (blockIdx.x * 256 + threadIdx.x) >> 6;
    int lane = threadIdx.x & 63;
    if (wid >= N_NODES) return;
    int i = wid;
    int rs = row_start[i], re = row_start[i + 1];
    int c = lane * 2;
    float a0 = 0.f, a1 = 0.f;
    int e = rs;
    for (; e + 3 < re; e += 4) {
        int s0 = csr_src[e], s1 = csr_src[e + 1], s2 = csr_src[e + 2], s3 = csr_src[e + 3];
        float d0 = dis[s0], d1 = dis[s1], d2 = dis[s2], d3 = dis[s3];
        float2 h0 = *(const float2*)&H[(size_t)s0 * NF + c];
        float2 h1 = *(const float2*)&H[(size_t)s1 * NF + c];
        float2 h2 = *(const float2*)&H[(size_t)s2 * NF + c];
        float2 h3 = *(const float2*)&H[(size_t)s3 * NF + c];
        a0 += d0 * h0.x + d1 * h1.x + d2 * h2.x + d3 * h3.x;
        a1 += d0 * h0.y + d1 * h1.y + d2 * h2.y + d3 * h3.y;
    }
    for (; e < re; e++) {
        int s = csr_src[e];
        float ds = dis[s];
        float2 h = *(const float2*)&H[(size_t)s * NF + c];
        a0 += ds * h.x;
        a1 += ds * h.y;
    }
    float di = dis[i], dv = dinv[i];
    float2 hs = *(const float2*)&H[(size_t)i * NF + c];
    float2 o;
    o.x = a0 * di + dv * hs.x + bias[c];
    o.y = a1 * di + dv * hs.y + bias[c + 1];
    *(float2*)&out[(size_t)i * NF + c] = o;
}

// ---------------------------------------------------------------- pooling
// batch is sorted; block handles 256 contiguous nodes, threads = 2 half-waves
// x 128 features; run-length accumulate, one atomic per (graph-run, feat).
__global__ void k_pool(const float* __restrict__ A, const int* __restrict__ batch,
                       float* __restrict__ sums) {
    int b = blockIdx.x, t = threadIdx.x;
    int c = t & 127, th = t >> 7;
    int start = b * 256 + th;
    if (start >= N_NODES) return;
    int end = min(N_NODES, b * 256 + 256);
    float acc = 0.f;
    int gcur = batch[start];
    for (int i = start; i < end; i += 2) {
        int g = batch[i];
        if (g != gcur) {
            atomicAdd(&sums[gcur * NF + c], acc);
            acc = 0.f;
            gcur = g;
        }
        acc += A[(size_t)i * NF + c];
    }
    atomicAdd(&sums[gcur * NF + c], acc);
}

// ---------------------------------------------------------------- heads
__global__ void k_head(const float* __restrict__ sums, const int* __restrict__ batch,
                       const float* __restrict__ wc, const float* __restrict__ bc,
                       const float* __restrict__ wr, const float* __restrict__ br,
                       float* __restrict__ out) {
    __shared__ float p[128];
    __shared__ int cnt_s;
    int g = blockIdx.x, c = threadIdx.x;
    if (c == 0) {
        int lo = 0, hi = N_NODES;
        while (lo < hi) { int m = (lo + hi) >> 1; if (batch[m] < g) lo = m + 1; else hi = m; }
        int s0 = lo;
        lo = 0; hi = N_NODES;
        while (lo < hi) { int m = (lo + hi) >> 1; if (batch[m] < g + 1) lo = m + 1; else hi = m; }
        cnt_s = lo - s0;
    }
    __syncthreads();
    float cnt = (float)max(cnt_s, 1);
    float pv = sums[g * NF + c] / cnt;
    p[c] = pv;
    out[g * NF + c] = pv;
    __syncthreads();
    if (c < N_CLASSES) {
        float d = bc[c];
        for (int k = 0; k < NF; k++) d += p[k] * wc[k * N_CLASSES + c];
        out[N_GRAPHS * NF + g * N_CLASSES + c] = d;
    }
    if (c == N_CLASSES) {
        float d = br[0];
        for (int k = 0; k < NF; k++) d += p[k] * wr[k];
        out[N_GRAPHS * NF + N_GRAPHS * N_CLASSES + g] = d;
    }
}

// ================================================================= launch
extern "C" void kernel_launch(void* const* d_in, const int* in_sizes, int n_in,
                              void* d_out, int out_size, void* d_ws, size_t ws_size,
                              hipStream_t stream) {
    const float* x     = (const float*)d_in[0];
    const int*   ei    = (const int*)d_in[1];
    const int*   batch = (const int*)d_in[2];
    const float* w0 = (const float*)d_in[3];
    const float* b0 = (const float*)d_in[4];
    const float* w1 = (const float*)d_in[5];
    const float* b1 = (const float*)d_in[6];
    const float* w2 = (const float*)d_in[7];
    const float* b2 = (const float*)d_in[8];
    const float* wc = (const float*)d_in[9];
    const float* bc = (const float*)d_in[10];
    const float* wr = (const float*)d_in[11];
    const float* br = (const float*)d_in[12];
    const int* srcp = ei;
    const int* dstp = ei + N_EDGES;
    float* out = (float*)d_out;

    char* ws = (char*)d_ws;
    size_t off = 0;
    auto alloc = [&](size_t bytes) -> void* {
        void* p = ws + off;
        off = (off + bytes + 255) & ~(size_t)255;
        return p;
    };
    int*   counts    = (int*)alloc(N_NODES * 4);
    int*   row_start = (int*)alloc((N_NODES + 1) * 4);
    int*   cursor    = (int*)alloc(N_NODES * 4);
    int*   bsum      = (int*)alloc(64 * 4);
    int*   boff      = (int*)alloc(64 * 4);
    float* dis       = (float*)alloc(N_NODES * 4);
    float* dinv      = (float*)alloc(N_NODES * 4);
    int*   csr_src   = (int*)alloc((size_t)N_EDGES * 4);
    float* Hbuf      = (float*)alloc((size_t)N_NODES * NF * 4);
    float* Abuf      = (float*)alloc((size_t)N_NODES * NF * 4);
    float* sums      = (float*)alloc(N_GRAPHS * NF * 4);
    (void)ws_size;

    const int nb = (N_NODES + 1023) / 1024;  // 49

    k_zero<<<(N_NODES + 255) / 256, 256, 0, stream>>>(counts, sums);
    k_count<<<(N_EDGES + 255) / 256, 256, 0, stream>>>(dstp, counts);
    k_scan_partial<<<nb, 256, 0, stream>>>(counts, bsum);
    k_scan_block<<<1, 64, 0, stream>>>(bsum, boff, row_start, nb);
    k_scan_final<<<nb, 256, 0, stream>>>(counts, boff, row_start, cursor, dis, dinv);
    k_fill<<<(N_EDGES + 255) / 256, 256, 0, stream>>>(srcp, dstp, cursor, csr_src);

    const int gemm_grid = (N_NODES + 63) / 64;   // 782
    const int agg_grid  = (N_NODES + 3) / 4;     // 12500

    // layer 0
    k_gemm<false><<<gemm_grid, 256, 0, stream>>>(x, w0, Hbuf);
    k_agg<<<agg_grid, 256, 0, stream>>>(Hbuf, b0, row_start, csr_src, dis, dinv, Abuf);
    // layer 1
    k_gemm<true><<<gemm_grid, 256, 0, stream>>>(Abuf, w1, Hbuf);
    k_agg<<<agg_grid, 256, 0, stream>>>(Hbuf, b1, row_start, csr_src, dis, dinv, Abuf);
    // layer 2
    k_gemm<true><<<gemm_grid, 256, 0, stream>>>(Abuf, w2, Hbuf);
    k_agg<<<agg_grid, 256, 0, stream>>>(Hbuf, b2, row_start, csr_src, dis, dinv, Abuf);

    k_pool<<<(N_NODES + 255) / 256, 256, 0, stream>>>(Abuf, batch, sums);
    k_head<<<N_GRAPHS, 128, 0, stream>>>(sums, batch, wc, bc, wr, br, out);
}

// Round 2
// 779.348 us; speedup vs baseline: 3.7060x; 3.7060x over previous
//
#include <hip/hip_runtime.h>
#include <math.h>

#define N_NODES   50000
#define N_EDGES   1600000
#define NF        128
#define N_GRAPHS  64
#define N_CLASSES 10

// ---------------------------------------------------------------- zero init
__global__ void k_zero(int* __restrict__ counts, float* __restrict__ sums) {
    int i = blockIdx.x * 256 + threadIdx.x;
    if (i < N_NODES) counts[i] = 0;
    if (i < N_GRAPHS * NF) sums[i] = 0.f;
}

// ---------------------------------------------------------------- in-degree
__global__ void k_count(const int* __restrict__ dst, int* __restrict__ counts) {
    int e = blockIdx.x * 256 + threadIdx.x;
    if (e < N_EDGES) atomicAdd(&counts[dst[e]], 1);
}

// ------------------------------------------------- scan step 1: block sums
__global__ void k_scan_partial(const int* __restrict__ counts, int* __restrict__ bsum) {
    __shared__ int sd[256];
    int b = blockIdx.x, t = threadIdx.x;
    int base = b * 1024 + t * 4;
    int s = 0;
#pragma unroll
    for (int j = 0; j < 4; j++) {
        int idx = base + j;
        if (idx < N_NODES) s += counts[idx];
    }
    sd[t] = s;
    __syncthreads();
    for (int off = 128; off > 0; off >>= 1) {
        if (t < off) sd[t] += sd[t + off];
        __syncthreads();
    }
    if (t == 0) bsum[b] = sd[0];
}

// ------------------------------------- scan step 2: serial scan of 49 sums
__global__ void k_scan_block(const int* __restrict__ bsum, int* __restrict__ boff,
                             int* __restrict__ row_start, int nb) {
    if (threadIdx.x == 0 && blockIdx.x == 0) {
        int run = 0;
        for (int b = 0; b < nb; b++) { boff[b] = run; run += bsum[b]; }
        row_start[N_NODES] = run;
    }
}

// -------------- scan step 3: per-element exclusive scan + node norm factors
__global__ void k_scan_final(const int* __restrict__ counts, const int* __restrict__ boff,
                             int* __restrict__ row_start, int* __restrict__ cursor,
                             float* __restrict__ dis, float* __restrict__ dinv) {
    __shared__ int sd[256];
    int b = blockIdx.x, t = threadIdx.x;
    int base = b * 1024 + t * 4;
    int v[4];
    int s = 0;
#pragma unroll
    for (int j = 0; j < 4; j++) {
        int idx = base + j;
        v[j] = (idx < N_NODES) ? counts[idx] : 0;
        s += v[j];
    }
    sd[t] = s;
    __syncthreads();
    // Hillis-Steele inclusive scan over 256 thread-sums
    for (int off = 1; off < 256; off <<= 1) {
        int y = (t >= off) ? sd[t - off] : 0;
        __syncthreads();
        sd[t] += y;
        __syncthreads();
    }
    int run = sd[t] - s + boff[b];
#pragma unroll
    for (int j = 0; j < 4; j++) {
        int idx = base + j;
        if (idx < N_NODES) {
            row_start[idx] = run;
            cursor[idx] = run;
            float df = (float)(v[j] + 1);  // deg incl. self-loop
            dis[idx]  = rsqrtf(df);
            dinv[idx] = 1.0f / df;
        }
        run += v[j];
    }
}

// ---------------------------------------------------------------- CSR fill
__global__ void k_fill(const int* __restrict__ src, const int* __restrict__ dst,
                       int* __restrict__ cursor, int* __restrict__ csr_src) {
    int e = blockIdx.x * 256 + threadIdx.x;
    if (e < N_EDGES) {
        int d = dst[e];
        int pos = atomicAdd(&cursor[d], 1);
        csr_src[pos] = src[e];
    }
}

// ---------------------------------------------------------------- GEMM
// H[r][c] = sum_k act(X[r][k]) * W[k][c].  64 rows x 128 cols per block,
// thread = 8 rows x 4 cols.  x staged in LDS (pad 132 breaks stride-128
// bank aliasing); w rows read from global (64 KB, L1/L2 resident, shared
// by all blocks).
//
// R1 fix: round-0 version had no unroll pragma on the k-loop -> compiler
// fully unrolled (trip 32), hoisted all loads, hit the 256-VGPR cap and
// spilled accumulators to scratch (rocprof: 771 MB WRITE_SIZE, VALUBusy 2%,
// 810 us). `#pragma unroll 2` + __launch_bounds__(256,4) keeps live set
// ~90 VGPRs, no spill, 4 blocks/CU.
template <bool ELU>
__global__ __launch_bounds__(256, 4) void k_gemm(const float* __restrict__ X,
                                                 const float* __restrict__ W,
                                                 float* __restrict__ H) {
    __shared__ float xs[64 * 132];
    int t = threadIdx.x;
    int row0 = blockIdx.x * 64;
#pragma unroll
    for (int i = 0; i < 8; i++) {
        int f = i * 256 + t;          // 0..2047 : 64 rows x 32 float4
        int r = f >> 5, c4 = (f & 31) * 4;
        float4 v = make_float4(0.f, 0.f, 0.f, 0.f);
        if (row0 + r < N_NODES) v = *(const float4*)&X[(size_t)(row0 + r) * NF + c4];
        if (ELU) {
            v.x = v.x > 0.f ? v.x : (expf(v.x) - 1.f);
            v.y = v.y > 0.f ? v.y : (expf(v.y) - 1.f);
            v.z = v.z > 0.f ? v.z : (expf(v.z) - 1.f);
            v.w = v.w > 0.f ? v.w : (expf(v.w) - 1.f);
        }
        *(float4*)&xs[r * 132 + c4] = v;
    }
    __syncthreads();

    int cg = t & 31;   // 4 cols: 4*cg..4*cg+3
    int rg = t >> 5;   // 8 rows: rg*8..rg*8+7
    float acc[8][4] = {};
#pragma unroll 2
    for (int k0 = 0; k0 < NF; k0 += 4) {
        float4 xv[8];
#pragma unroll
        for (int rr = 0; rr < 8; rr++)
            xv[rr] = *(const float4*)&xs[(rg * 8 + rr) * 132 + k0];
#pragma unroll
        for (int kk = 0; kk < 4; kk++) {
            float4 wv = *(const float4*)&W[(k0 + kk) * NF + cg * 4];
#pragma unroll
            for (int rr = 0; rr < 8; rr++) {
                float xk = (kk == 0) ? xv[rr].x : (kk == 1) ? xv[rr].y
                         : (kk == 2) ? xv[rr].z : xv[rr].w;
                acc[rr][0] += xk * wv.x;
                acc[rr][1] += xk * wv.y;
                acc[rr][2] += xk * wv.z;
                acc[rr][3] += xk * wv.w;
            }
        }
    }
#pragma unroll
    for (int rr = 0; rr < 8; rr++) {
        int r = row0 + rg * 8 + rr;
        if (r < N_NODES) {
            float4 o = make_float4(acc[rr][0], acc[rr][1], acc[rr][2], acc[rr][3]);
            *(float4*)&H[(size_t)r * NF + cg * 4] = o;
        }
    }
}

// ------------------------------------------------------------- aggregation
// One wave per node; lane holds features 2*lane, 2*lane+1.
// out[i] = dis[i] * sum_e dis[src_e] * H[src_e] + dinv[i]*H[i] + b
__global__ __launch_bounds__(256) void k_agg(const float* __restrict__ H,
                                             const float* __restrict__ bias,
                                             const int* __restrict__ row_start,
                                             const int* __restrict__ csr_src,
                                             const float* __restrict__ dis,
                                             const float* __restrict__ dinv,
                                             float* __restrict__ out) {
    int wid  = (blockIdx.x * 256 + threadIdx.x) >> 6;
    int lane = threadIdx.x & 63;
    if (wid >= N_NODES) return;
    int i = wid;
    int rs = row_start[i], re = row_start[i + 1];
    int c = lane * 2;
    float a0 = 0.f, a1 = 0.f;
    int e = rs;
    for (; e + 3 < re; e += 4) {
        int s0 = csr_src[e], s1 = csr_src[e + 1], s2 = csr_src[e + 2], s3 = csr_src[e + 3];
        float d0 = dis[s0], d1 = dis[s1], d2 = dis[s2], d3 = dis[s3];
        float2 h0 = *(const float2*)&H[(size_t)s0 * NF + c];
        float2 h1 = *(const float2*)&H[(size_t)s1 * NF + c];
        float2 h2 = *(const float2*)&H[(size_t)s2 * NF + c];
        float2 h3 = *(const float2*)&H[(size_t)s3 * NF + c];
        a0 += d0 * h0.x + d1 * h1.x + d2 * h2.x + d3 * h3.x;
        a1 += d0 * h0.y + d1 * h1.y + d2 * h2.y + d3 * h3.y;
    }
    for (; e < re; e++) {
        int s = csr_src[e];
        float ds = dis[s];
        float2 h = *(const float2*)&H[(size_t)s * NF + c];
        a0 += ds * h.x;
        a1 += ds * h.y;
    }
    float di = dis[i], dv = dinv[i];
    float2 hs = *(const float2*)&H[(size_t)i * NF + c];
    float2 o;
    o.x = a0 * di + dv * hs.x + bias[c];
    o.y = a1 * di + dv * hs.y + bias[c + 1];
    *(float2*)&out[(size_t)i * NF + c] = o;
}

// ---------------------------------------------------------------- pooling
// batch is sorted; block handles 256 contiguous nodes, threads = 2 half-waves
// x 128 features; run-length accumulate, one atomic per (graph-run, feat).
__global__ void k_pool(const float* __restrict__ A, const int* __restrict__ batch,
                       float* __restrict__ sums) {
    int b = blockIdx.x, t = threadIdx.x;
    int c = t & 127, th = t >> 7;
    int start = b * 256 + th;
    if (start >= N_NODES) return;
    int end = min(N_NODES, b * 256 + 256);
    float acc = 0.f;
    int gcur = batch[start];
    for (int i = start; i < end; i += 2) {
        int g = batch[i];
        if (g != gcur) {
            atomicAdd(&sums[gcur * NF + c], acc);
            acc = 0.f;
            gcur = g;
        }
        acc += A[(size_t)i * NF + c];
    }
    atomicAdd(&sums[gcur * NF + c], acc);
}

// ---------------------------------------------------------------- heads
__global__ void k_head(const float* __restrict__ sums, const int* __restrict__ batch,
                       const float* __restrict__ wc, const float* __restrict__ bc,
                       const float* __restrict__ wr, const float* __restrict__ br,
                       float* __restrict__ out) {
    __shared__ float p[128];
    __shared__ int cnt_s;
    int g = blockIdx.x, c = threadIdx.x;
    if (c == 0) {
        int lo = 0, hi = N_NODES;
        while (lo < hi) { int m = (lo + hi) >> 1; if (batch[m] < g) lo = m + 1; else hi = m; }
        int s0 = lo;
        lo = 0; hi = N_NODES;
        while (lo < hi) { int m = (lo + hi) >> 1; if (batch[m] < g + 1) lo = m + 1; else hi = m; }
        cnt_s = lo - s0;
    }
    __syncthreads();
    float cnt = (float)max(cnt_s, 1);
    float pv = sums[g * NF + c] / cnt;
    p[c] = pv;
    out[g * NF + c] = pv;
    __syncthreads();
    if (c < N_CLASSES) {
        float d = bc[c];
        for (int k = 0; k < NF; k++) d += p[k] * wc[k * N_CLASSES + c];
        out[N_GRAPHS * NF + g * N_CLASSES + c] = d;
    }
    if (c == N_CLASSES) {
        float d = br[0];
        for (int k = 0; k < NF; k++) d += p[k] * wr[k];
        out[N_GRAPHS * NF + N_GRAPHS * N_CLASSES + g] = d;
    }
}

// ================================================================= launch
extern "C" void kernel_launch(void* const* d_in, const int* in_sizes, int n_in,
                              void* d_out, int out_size, void* d_ws, size_t ws_size,
                              hipStream_t stream) {
    const float* x     = (const float*)d_in[0];
    const int*   ei    = (const int*)d_in[1];
    const int*   batch = (const int*)d_in[2];
    const float* w0 = (const float*)d_in[3];
    const float* b0 = (const float*)d_in[4];
    const float* w1 = (const float*)d_in[5];
    const float* b1 = (const float*)d_in[6];
    const float* w2 = (const float*)d_in[7];
    const float* b2 = (const float*)d_in[8];
    const float* wc = (const float*)d_in[9];
    const float* bc = (const float*)d_in[10];
    const float* wr = (const float*)d_in[11];
    const float* br = (const float*)d_in[12];
    const int* srcp = ei;
    const int* dstp = ei + N_EDGES;
    float* out = (float*)d_out;

    char* ws = (char*)d_ws;
    size_t off = 0;
    auto alloc = [&](size_t bytes) -> void* {
        void* p = ws + off;
        off = (off + bytes + 255) & ~(size_t)255;
        return p;
    };
    int*   counts    = (int*)alloc(N_NODES * 4);
    int*   row_start = (int*)alloc((N_NODES + 1) * 4);
    int*   cursor    = (int*)alloc(N_NODES * 4);
    int*   bsum      = (int*)alloc(64 * 4);
    int*   boff      = (int*)alloc(64 * 4);
    float* dis       = (float*)alloc(N_NODES * 4);
    float* dinv      = (float*)alloc(N_NODES * 4);
    int*   csr_src   = (int*)alloc((size_t)N_EDGES * 4);
    float* Hbuf      = (float*)alloc((size_t)N_NODES * NF * 4);
    float* Abuf      = (float*)alloc((size_t)N_NODES * NF * 4);
    float* sums      = (float*)alloc(N_GRAPHS * NF * 4);
    (void)ws_size;

    const int nb = (N_NODES + 1023) / 1024;  // 49

    k_zero<<<(N_NODES + 255) / 256, 256, 0, stream>>>(counts, sums);
    k_count<<<(N_EDGES + 255) / 256, 256, 0, stream>>>(dstp, counts);
    k_scan_partial<<<nb, 256, 0, stream>>>(counts, bsum);
    k_scan_block<<<1, 64, 0, stream>>>(bsum, boff, row_start, nb);
    k_scan_final<<<nb, 256, 0, stream>>>(counts, boff, row_start, cursor, dis, dinv);
    k_fill<<<(N_EDGES + 255) / 256, 256, 0, stream>>>(srcp, dstp, cursor, csr_src);

    const int gemm_grid = (N_NODES + 63) / 64;   // 782
    const int agg_grid  = (N_NODES + 3) / 4;     // 12500

    // layer 0
    k_gemm<false><<<gemm_grid, 256, 0, stream>>>(x, w0, Hbuf);
    k_agg<<<agg_grid, 256, 0, stream>>>(Hbuf, b0, row_start, csr_src, dis, dinv, Abuf);
    // layer 1
    k_gemm<true><<<gemm_grid, 256, 0, stream>>>(Abuf, w1, Hbuf);
    k_agg<<<agg_grid, 256, 0, stream>>>(Hbuf, b1, row_start, csr_src, dis, dinv, Abuf);
    // layer 2
    k_gemm<true><<<gemm_grid, 256, 0, stream>>>(Abuf, w2, Hbuf);
    k_agg<<<agg_grid, 256, 0, stream>>>(Hbuf, b2, row_start, csr_src, dis, dinv, Abuf);

    k_pool<<<(N_NODES + 255) / 256, 256, 0, stream>>>(Abuf, batch, sums);
    k_head<<<N_GRAPHS, 128, 0, stream>>>(sums, batch, wc, bc, wr, br, out);
}

// Round 3
// 671.565 us; speedup vs baseline: 4.3008x; 1.1605x over previous
//
#include <hip/hip_runtime.h>
#include <math.h>

#define N_NODES   50000
#define N_EDGES   1600000
#define NF        128
#define N_GRAPHS  64
#define N_CLASSES 10

#define NBK       98        // buckets: dst>>9, 512 nodes each (98*512 = 50176)
#define BK_SHIFT  9
#define BK_NODES  512
#define CHUNK     8192
#define NCHUNKS   ((N_EDGES + CHUNK - 1) / CHUNK)   // 196

// ---------------------------------------------------------------- zero init
__global__ void k_zero(int* __restrict__ bucket_cnt, float* __restrict__ sums) {
    int i = blockIdx.x * 256 + threadIdx.x;
    if (i < NBK) bucket_cnt[i] = 0;
    if (i < N_GRAPHS * NF) sums[i] = 0.f;
}

// ------------------------------------------- P1: per-bucket edge histogram
__global__ __launch_bounds__(256) void k_bcount(const int* __restrict__ dst,
                                                int* __restrict__ bucket_cnt) {
    __shared__ int h[NBK];
    int t = threadIdx.x;
    if (t < NBK) h[t] = 0;
    __syncthreads();
    int base = blockIdx.x * CHUNK;
    int end = min(base + CHUNK, N_EDGES);
    for (int e = base + t; e < end; e += 256)
        atomicAdd(&h[dst[e] >> BK_SHIFT], 1);
    __syncthreads();
    if (t < NBK && h[t]) atomicAdd(&bucket_cnt[t], h[t]);
}

// ------------------------------------------------- P2: scan the 98 buckets
__global__ void k_bscan(const int* __restrict__ bucket_cnt, int* __restrict__ bucket_off,
                        int* __restrict__ bucket_cursor, int* __restrict__ row_start) {
    if (threadIdx.x == 0 && blockIdx.x == 0) {
        int run = 0;
        for (int b = 0; b < NBK; b++) {
            bucket_off[b] = run;
            bucket_cursor[b] = run;
            run += bucket_cnt[b];
        }
        bucket_off[NBK] = run;          // == N_EDGES
        row_start[N_NODES] = run;
    }
}

// --------------------------- P3: scatter pairs into bucket-grouped storage
// Per-workgroup histogram -> one global reservation per (wg,bucket) -> each
// wg owns contiguous ~1KB runs, so L2 assembles full lines (no HBM write
// amplification; round-2 k_fill wrote 101 MB for 6.4 MB of payload).
__global__ __launch_bounds__(256) void k_bscatter(const int* __restrict__ src,
                                                  const int* __restrict__ dst,
                                                  int* __restrict__ bucket_cursor,
                                                  int2* __restrict__ pairs) {
    __shared__ int h[NBK], rb[NBK], c2[NBK];
    int t = threadIdx.x;
    if (t < NBK) { h[t] = 0; c2[t] = 0; }
    __syncthreads();
    int base = blockIdx.x * CHUNK;
    int end = min(base + CHUNK, N_EDGES);
    for (int e = base + t; e < end; e += 256)
        atomicAdd(&h[dst[e] >> BK_SHIFT], 1);
    __syncthreads();
    if (t < NBK) rb[t] = h[t] ? atomicAdd(&bucket_cursor[t], h[t]) : 0;
    __syncthreads();
    for (int e = base + t; e < end; e += 256) {
        int d = dst[e];
        int b = d >> BK_SHIFT;
        int k = atomicAdd(&c2[b], 1);
        pairs[rb[b] + k] = make_int2(src[e], d);
    }
}

// ----------------- P4: per-bucket CSR finalize (counts, scan, norms, fill)
// One wg per bucket; all csr_src writes for the bucket's ~65 KB region come
// from this wg (one XCD) -> compact HBM writes. Also replaces the global
// k_count + 50K-element scan: per-node degree lives in LDS.
__global__ __launch_bounds__(256) void k_bfill(const int2* __restrict__ pairs,
                                               const int* __restrict__ bucket_off,
                                               int* __restrict__ row_start,
                                               float* __restrict__ dis,
                                               float* __restrict__ dinv,
                                               int* __restrict__ csr_src) {
    __shared__ int cnt[BK_NODES];
    __shared__ int cur[BK_NODES];
    __shared__ int ts[256];
    int b = blockIdx.x, t = threadIdx.x;
    int node_base = b << BK_SHIFT;
    int lo = bucket_off[b], hi = bucket_off[b + 1];

    cnt[t] = 0; cnt[t + 256] = 0;
    __syncthreads();
    for (int e = lo + t; e < hi; e += 256)
        atomicAdd(&cnt[pairs[e].y & (BK_NODES - 1)], 1);
    __syncthreads();

    int a0 = cnt[2 * t], a1 = cnt[2 * t + 1];
    ts[t] = a0 + a1;
    __syncthreads();
    for (int off = 1; off < 256; off <<= 1) {
        int y = (t >= off) ? ts[t - off] : 0;
        __syncthreads();
        ts[t] += y;
        __syncthreads();
    }
    int ex = ts[t] - (a0 + a1);          // exclusive scan of this thread's 2 nodes
    int row0 = lo + ex;
    int row1 = row0 + a0;
    cur[2 * t] = row0;
    cur[2 * t + 1] = row1;
    int n0 = node_base + 2 * t, n1 = node_base + 2 * t + 1;
    if (n0 < N_NODES) {
        row_start[n0] = row0;
        float df = (float)(a0 + 1);
        dis[n0] = rsqrtf(df);
        dinv[n0] = 1.0f / df;
    }
    if (n1 < N_NODES) {
        row_start[n1] = row1;
        float df = (float)(a1 + 1);
        dis[n1] = rsqrtf(df);
        dinv[n1] = 1.0f / df;
    }
    __syncthreads();

    for (int e = lo + t; e < hi; e += 256) {
        int2 p = pairs[e];
        int pos = atomicAdd(&cur[p.y & (BK_NODES - 1)], 1);
        csr_src[pos] = p.x;
    }
}

// ---------------------------------------------------------------- GEMM
// H[r][c] = sum_k act(X[r][k]) * W[k][c].  64 rows x 128 cols per block,
// thread = 8 rows x 4 cols.  x staged in LDS (pad 132 breaks stride-128
// bank aliasing); w rows read from global (64 KB, L1/L2 resident).
// `#pragma unroll 2` + __launch_bounds__(256,4): round-0's full unroll
// spilled (256 VGPR cap, 771 MB scratch writes, 810 us -> 30 us).
template <bool ELU>
__global__ __launch_bounds__(256, 4) void k_gemm(const float* __restrict__ X,
                                                 const float* __restrict__ W,
                                                 float* __restrict__ H) {
    __shared__ float xs[64 * 132];
    int t = threadIdx.x;
    int row0 = blockIdx.x * 64;
#pragma unroll
    for (int i = 0; i < 8; i++) {
        int f = i * 256 + t;          // 0..2047 : 64 rows x 32 float4
        int r = f >> 5, c4 = (f & 31) * 4;
        float4 v = make_float4(0.f, 0.f, 0.f, 0.f);
        if (row0 + r < N_NODES) v = *(const float4*)&X[(size_t)(row0 + r) * NF + c4];
        if (ELU) {
            v.x = v.x > 0.f ? v.x : (expf(v.x) - 1.f);
            v.y = v.y > 0.f ? v.y : (expf(v.y) - 1.f);
            v.z = v.z > 0.f ? v.z : (expf(v.z) - 1.f);
            v.w = v.w > 0.f ? v.w : (expf(v.w) - 1.f);
        }
        *(float4*)&xs[r * 132 + c4] = v;
    }
    __syncthreads();

    int cg = t & 31;   // 4 cols: 4*cg..4*cg+3
    int rg = t >> 5;   // 8 rows: rg*8..rg*8+7
    float acc[8][4] = {};
#pragma unroll 2
    for (int k0 = 0; k0 < NF; k0 += 4) {
        float4 xv[8];
#pragma unroll
        for (int rr = 0; rr < 8; rr++)
            xv[rr] = *(const float4*)&xs[(rg * 8 + rr) * 132 + k0];
#pragma unroll
        for (int kk = 0; kk < 4; kk++) {
            float4 wv = *(const float4*)&W[(k0 + kk) * NF + cg * 4];
#pragma unroll
            for (int rr = 0; rr < 8; rr++) {
                float xk = (kk == 0) ? xv[rr].x : (kk == 1) ? xv[rr].y
                         : (kk == 2) ? xv[rr].z : xv[rr].w;
                acc[rr][0] += xk * wv.x;
                acc[rr][1] += xk * wv.y;
                acc[rr][2] += xk * wv.z;
                acc[rr][3] += xk * wv.w;
            }
        }
    }
#pragma unroll
    for (int rr = 0; rr < 8; rr++) {
        int r = row0 + rg * 8 + rr;
        if (r < N_NODES) {
            float4 o = make_float4(acc[rr][0], acc[rr][1], acc[rr][2], acc[rr][3]);
            *(float4*)&H[(size_t)r * NF + cg * 4] = o;
        }
    }
}

// ------------------------------------------------------------- aggregation
// One wave per node; lane holds features 2*lane, 2*lane+1.
// out[i] = dis[i] * sum_e dis[src_e] * H[src_e] + dinv[i]*H[i] + b
__global__ __launch_bounds__(256) void k_agg(const float* __restrict__ H,
                                             const float* __restrict__ bias,
                                             const int* __restrict__ row_start,
                                             const int* __restrict__ csr_src,
                                             const float* __restrict__ dis,
                                             const float* __restrict__ dinv,
                                             float* __restrict__ out) {
    int wid  = (blockIdx.x * 256 + threadIdx.x) >> 6;
    int lane = threadIdx.x & 63;
    if (wid >= N_NODES) return;
    int i = wid;
    int rs = row_start[i], re = row_start[i + 1];
    int c = lane * 2;
    float a0 = 0.f, a1 = 0.f;
    int e = rs;
    for (; e + 3 < re; e += 4) {
        int s0 = csr_src[e], s1 = csr_src[e + 1], s2 = csr_src[e + 2], s3 = csr_src[e + 3];
        float d0 = dis[s0], d1 = dis[s1], d2 = dis[s2], d3 = dis[s3];
        float2 h0 = *(const float2*)&H[(size_t)s0 * NF + c];
        float2 h1 = *(const float2*)&H[(size_t)s1 * NF + c];
        float2 h2 = *(const float2*)&H[(size_t)s2 * NF + c];
        float2 h3 = *(const float2*)&H[(size_t)s3 * NF + c];
        a0 += d0 * h0.x + d1 * h1.x + d2 * h2.x + d3 * h3.x;
        a1 += d0 * h0.y + d1 * h1.y + d2 * h2.y + d3 * h3.y;
    }
    for (; e < re; e++) {
        int s = csr_src[e];
        float ds = dis[s];
        float2 h = *(const float2*)&H[(size_t)s * NF + c];
        a0 += ds * h.x;
        a1 += ds * h.y;
    }
    float di = dis[i], dv = dinv[i];
    float2 hs = *(const float2*)&H[(size_t)i * NF + c];
    float2 o;
    o.x = a0 * di + dv * hs.x + bias[c];
    o.y = a1 * di + dv * hs.y + bias[c + 1];
    *(float2*)&out[(size_t)i * NF + c] = o;
}

// ---------------------------------------------------------------- pooling
__global__ void k_pool(const float* __restrict__ A, const int* __restrict__ batch,
                       float* __restrict__ sums) {
    int b = blockIdx.x, t = threadIdx.x;
    int c = t & 127, th = t >> 7;
    int start = b * 256 + th;
    if (start >= N_NODES) return;
    int end = min(N_NODES, b * 256 + 256);
    float acc = 0.f;
    int gcur = batch[start];
    for (int i = start; i < end; i += 2) {
        int g = batch[i];
        if (g != gcur) {
            atomicAdd(&sums[gcur * NF + c], acc);
            acc = 0.f;
            gcur = g;
        }
        acc += A[(size_t)i * NF + c];
    }
    atomicAdd(&sums[gcur * NF + c], acc);
}

// ---------------------------------------------------------------- heads
__global__ void k_head(const float* __restrict__ sums, const int* __restrict__ batch,
                       const float* __restrict__ wc, const float* __restrict__ bc,
                       const float* __restrict__ wr, const float* __restrict__ br,
                       float* __restrict__ out) {
    __shared__ float p[128];
    __shared__ int cnt_s;
    int g = blockIdx.x, c = threadIdx.x;
    if (c == 0) {
        int lo = 0, hi = N_NODES;
        while (lo < hi) { int m = (lo + hi) >> 1; if (batch[m] < g) lo = m + 1; else hi = m; }
        int s0 = lo;
        lo = 0; hi = N_NODES;
        while (lo < hi) { int m = (lo + hi) >> 1; if (batch[m] < g + 1) lo = m + 1; else hi = m; }
        cnt_s = lo - s0;
    }
    __syncthreads();
    float cnt = (float)max(cnt_s, 1);
    float pv = sums[g * NF + c] / cnt;
    p[c] = pv;
    out[g * NF + c] = pv;
    __syncthreads();
    if (c < N_CLASSES) {
        float d = bc[c];
        for (int k = 0; k < NF; k++) d += p[k] * wc[k * N_CLASSES + c];
        out[N_GRAPHS * NF + g * N_CLASSES + c] = d;
    }
    if (c == N_CLASSES) {
        float d = br[0];
        for (int k = 0; k < NF; k++) d += p[k] * wr[k];
        out[N_GRAPHS * NF + N_GRAPHS * N_CLASSES + g] = d;
    }
}

// ================================================================= launch
extern "C" void kernel_launch(void* const* d_in, const int* in_sizes, int n_in,
                              void* d_out, int out_size, void* d_ws, size_t ws_size,
                              hipStream_t stream) {
    const float* x     = (const float*)d_in[0];
    const int*   ei    = (const int*)d_in[1];
    const int*   batch = (const int*)d_in[2];
    const float* w0 = (const float*)d_in[3];
    const float* b0 = (const float*)d_in[4];
    const float* w1 = (const float*)d_in[5];
    const float* b1 = (const float*)d_in[6];
    const float* w2 = (const float*)d_in[7];
    const float* b2 = (const float*)d_in[8];
    const float* wc = (const float*)d_in[9];
    const float* bc = (const float*)d_in[10];
    const float* wr = (const float*)d_in[11];
    const float* br = (const float*)d_in[12];
    const int* srcp = ei;
    const int* dstp = ei + N_EDGES;
    float* out = (float*)d_out;

    char* ws = (char*)d_ws;
    size_t off = 0;
    auto alloc = [&](size_t bytes) -> void* {
        void* p = ws + off;
        off = (off + bytes + 255) & ~(size_t)255;
        return p;
    };
    int*   row_start  = (int*)alloc((N_NODES + 1) * 4);
    int*   bucket_cnt = (int*)alloc(NBK * 4);
    int*   bucket_off = (int*)alloc((NBK + 1) * 4);
    int*   bucket_cur = (int*)alloc(NBK * 4);
    float* dis        = (float*)alloc(N_NODES * 4);
    float* dinv       = (float*)alloc(N_NODES * 4);
    int*   csr_src    = (int*)alloc((size_t)N_EDGES * 4);
    float* Hbuf       = (float*)alloc((size_t)N_NODES * NF * 4);
    float* Abuf       = (float*)alloc((size_t)N_NODES * NF * 4);
    float* sums       = (float*)alloc(N_GRAPHS * NF * 4);
    (void)ws_size;
    // pairs (12.8 MB) aliases Hbuf (25.6 MB): only live before the first GEMM.
    int2* pairs = (int2*)Hbuf;

    k_zero<<<(N_GRAPHS * NF + 255) / 256, 256, 0, stream>>>(bucket_cnt, sums);
    k_bcount<<<NCHUNKS, 256, 0, stream>>>(dstp, bucket_cnt);
    k_bscan<<<1, 64, 0, stream>>>(bucket_cnt, bucket_off, bucket_cur, row_start);
    k_bscatter<<<NCHUNKS, 256, 0, stream>>>(srcp, dstp, bucket_cur, pairs);
    k_bfill<<<NBK, 256, 0, stream>>>(pairs, bucket_off, row_start, dis, dinv, csr_src);

    const int gemm_grid = (N_NODES + 63) / 64;   // 782
    const int agg_grid  = (N_NODES + 3) / 4;     // 12500

    // layer 0
    k_gemm<false><<<gemm_grid, 256, 0, stream>>>(x, w0, Hbuf);
    k_agg<<<agg_grid, 256, 0, stream>>>(Hbuf, b0, row_start, csr_src, dis, dinv, Abuf);
    // layer 1
    k_gemm<true><<<gemm_grid, 256, 0, stream>>>(Abuf, w1, Hbuf);
    k_agg<<<agg_grid, 256, 0, stream>>>(Hbuf, b1, row_start, csr_src, dis, dinv, Abuf);
    // layer 2
    k_gemm<true><<<gemm_grid, 256, 0, stream>>>(Abuf, w2, Hbuf);
    k_agg<<<agg_grid, 256, 0, stream>>>(Hbuf, b2, row_start, csr_src, dis, dinv, Abuf);

    k_pool<<<(N_NODES + 255) / 256, 256, 0, stream>>>(Abuf, batch, sums);
    k_head<<<N_GRAPHS, 128, 0, stream>>>(sums, batch, wc, bc, wr, br, out);
}

// Round 4
// 491.434 us; speedup vs baseline: 5.8772x; 1.3665x over previous
//
#include <hip/hip_runtime.h>
#include <hip/hip_fp16.h>
#include <math.h>

#define N_NODES   50000
#define N_EDGES   1600000
#define NF        128
#define N_GRAPHS  64
#define N_CLASSES 10

#define NBK       391       // buckets: dst>>7, 128 nodes each (391*128 = 50048)
#define BK_SHIFT  7
#define BK_NODES  128
#define CHUNK     8192
#define NCHUNKS   ((N_EDGES + CHUNK - 1) / CHUNK)   // 196

// ---------------------------------------------------------------- zero init
__global__ void k_zero(int* __restrict__ bucket_cnt, float* __restrict__ sums) {
    int i = blockIdx.x * 256 + threadIdx.x;
    if (i < NBK) bucket_cnt[i] = 0;
    if (i < N_GRAPHS * NF) sums[i] = 0.f;
}

// ------------------------------------------- P1: per-bucket edge histogram
__global__ __launch_bounds__(256) void k_bcount(const int* __restrict__ dst,
                                                int* __restrict__ bucket_cnt) {
    __shared__ int h[NBK];
    int t = threadIdx.x;
    for (int i = t; i < NBK; i += 256) h[i] = 0;
    __syncthreads();
    int base = blockIdx.x * CHUNK;
    int end = min(base + CHUNK, N_EDGES);
    for (int e = base + t; e < end; e += 256)
        atomicAdd(&h[dst[e] >> BK_SHIFT], 1);
    __syncthreads();
    for (int i = t; i < NBK; i += 256)
        if (h[i]) atomicAdd(&bucket_cnt[i], h[i]);
}

// ------------------------------------------------ P2: scan the 391 buckets
__global__ void k_bscan(const int* __restrict__ bucket_cnt, int* __restrict__ bucket_off,
                        int* __restrict__ bucket_cursor, int* __restrict__ row_start) {
    if (threadIdx.x == 0 && blockIdx.x == 0) {
        int run = 0;
        for (int b = 0; b < NBK; b++) {
            bucket_off[b] = run;
            bucket_cursor[b] = run;
            run += bucket_cnt[b];
        }
        bucket_off[NBK] = run;          // == N_EDGES
        row_start[N_NODES] = run;
    }
}

// --------------------------- P3: scatter pairs into bucket-grouped storage
// Per-workgroup histogram -> one global reservation per (wg,bucket) -> each
// wg owns contiguous runs, so L2 assembles full lines (round-2's direct
// scatter wrote 101 MB HBM for 6.4 MB payload; this structure fixed it).
__global__ __launch_bounds__(256) void k_bscatter(const int* __restrict__ src,
                                                  const int* __restrict__ dst,
                                                  int* __restrict__ bucket_cursor,
                                                  int2* __restrict__ pairs) {
    __shared__ int h[NBK], rb[NBK], c2[NBK];
    int t = threadIdx.x;
    for (int i = t; i < NBK; i += 256) { h[i] = 0; c2[i] = 0; }
    __syncthreads();
    int base = blockIdx.x * CHUNK;
    int end = min(base + CHUNK, N_EDGES);
    for (int e = base + t; e < end; e += 256)
        atomicAdd(&h[dst[e] >> BK_SHIFT], 1);
    __syncthreads();
    for (int i = t; i < NBK; i += 256)
        rb[i] = h[i] ? atomicAdd(&bucket_cursor[i], h[i]) : 0;
    __syncthreads();
    for (int e = base + t; e < end; e += 256) {
        int d = dst[e];
        int b = d >> BK_SHIFT;
        int k = atomicAdd(&c2[b], 1);
        pairs[rb[b] + k] = make_int2(src[e], d);
    }
}

// ----------------- P4: per-bucket CSR finalize (counts, scan, norms, fill)
// One wg per 128-node bucket (391 wgs; round-3's 98 wgs under-occupied).
__global__ __launch_bounds__(256) void k_bfill(const int2* __restrict__ pairs,
                                               const int* __restrict__ bucket_off,
                                               int* __restrict__ row_start,
                                               float* __restrict__ dis,
                                               float* __restrict__ dinv,
                                               int* __restrict__ csr_src) {
    __shared__ int cnt[BK_NODES];
    __shared__ int cur[BK_NODES];
    __shared__ int ts[256];
    int b = blockIdx.x, t = threadIdx.x;
    int node_base = b << BK_SHIFT;
    int lo = bucket_off[b], hi = bucket_off[b + 1];

    if (t < BK_NODES) cnt[t] = 0;
    __syncthreads();
    for (int e = lo + t; e < hi; e += 256)
        atomicAdd(&cnt[pairs[e].y & (BK_NODES - 1)], 1);
    __syncthreads();

    int a = (t < BK_NODES) ? cnt[t] : 0;
    ts[t] = a;
    __syncthreads();
    for (int off = 1; off < 256; off <<= 1) {
        int y = (t >= off) ? ts[t - off] : 0;
        __syncthreads();
        ts[t] += y;
        __syncthreads();
    }
    int row = lo + ts[t] - a;            // exclusive scan
    if (t < BK_NODES) {
        cur[t] = row;
        int n = node_base + t;
        if (n < N_NODES) {
            row_start[n] = row;
            float df = (float)(a + 1);   // deg incl. self-loop
            dis[n]  = rsqrtf(df);
            dinv[n] = 1.0f / df;
        }
    }
    __syncthreads();

    for (int e = lo + t; e < hi; e += 256) {
        int2 p = pairs[e];
        int pos = atomicAdd(&cur[p.y & (BK_NODES - 1)], 1);
        csr_src[pos] = p.x;
    }
}

// ---------------------------------------------------------------- GEMM
// H[r][c] = sum_k act(X[r][k]) * W[k][c], fp32 accumulate, fp16 store.
// fp16 H halves the round-3 k_agg gather traffic (361 MB L2-miss / 108 us).
// 64 rows x 128 cols per block, thread = 8 rows x 4 cols; x staged in LDS
// (pad 132 breaks stride-128 bank aliasing); w via L1/L2.
// `#pragma unroll 2` + __launch_bounds__(256,4): round-0's full unroll
// spilled (256 VGPR cap, 771 MB scratch writes, 810 us -> 30 us).
template <bool ELU>
__global__ __launch_bounds__(256, 4) void k_gemm(const float* __restrict__ X,
                                                 const float* __restrict__ W,
                                                 __half* __restrict__ H) {
    __shared__ float xs[64 * 132];
    int t = threadIdx.x;
    int row0 = blockIdx.x * 64;
#pragma unroll
    for (int i = 0; i < 8; i++) {
        int f = i * 256 + t;          // 0..2047 : 64 rows x 32 float4
        int r = f >> 5, c4 = (f & 31) * 4;
        float4 v = make_float4(0.f, 0.f, 0.f, 0.f);
        if (row0 + r < N_NODES) v = *(const float4*)&X[(size_t)(row0 + r) * NF + c4];
        if (ELU) {
            v.x = v.x > 0.f ? v.x : (expf(v.x) - 1.f);
            v.y = v.y > 0.f ? v.y : (expf(v.y) - 1.f);
            v.z = v.z > 0.f ? v.z : (expf(v.z) - 1.f);
            v.w = v.w > 0.f ? v.w : (expf(v.w) - 1.f);
        }
        *(float4*)&xs[r * 132 + c4] = v;
    }
    __syncthreads();

    int cg = t & 31;   // 4 cols: 4*cg..4*cg+3
    int rg = t >> 5;   // 8 rows: rg*8..rg*8+7
    float acc[8][4] = {};
#pragma unroll 2
    for (int k0 = 0; k0 < NF; k0 += 4) {
        float4 xv[8];
#pragma unroll
        for (int rr = 0; rr < 8; rr++)
            xv[rr] = *(const float4*)&xs[(rg * 8 + rr) * 132 + k0];
#pragma unroll
        for (int kk = 0; kk < 4; kk++) {
            float4 wv = *(const float4*)&W[(k0 + kk) * NF + cg * 4];
#pragma unroll
            for (int rr = 0; rr < 8; rr++) {
                float xk = (kk == 0) ? xv[rr].x : (kk == 1) ? xv[rr].y
                         : (kk == 2) ? xv[rr].z : xv[rr].w;
                acc[rr][0] += xk * wv.x;
                acc[rr][1] += xk * wv.y;
                acc[rr][2] += xk * wv.z;
                acc[rr][3] += xk * wv.w;
            }
        }
    }
#pragma unroll
    for (int rr = 0; rr < 8; rr++) {
        int r = row0 + rg * 8 + rr;
        if (r < N_NODES) {
            union { __half2 h2[2]; float2 f2; } u;
            u.h2[0] = __floats2half2_rn(acc[rr][0], acc[rr][1]);
            u.h2[1] = __floats2half2_rn(acc[rr][2], acc[rr][3]);
            *(float2*)&H[(size_t)r * NF + cg * 4] = u.f2;
        }
    }
}

// ------------------------------------------------------------- aggregation
// One wave per node; lane holds features 2*lane, 2*lane+1 (one __half2).
// out[i] = dis[i] * sum_e dis[src_e] * H[src_e] + dinv[i]*H[i] + b
__global__ __launch_bounds__(256) void k_agg(const __half* __restrict__ H,
                                             const float* __restrict__ bias,
                                             const int* __restrict__ row_start,
                                             const int* __restrict__ csr_src,
                                             const float* __restrict__ dis,
                                             const float* __restrict__ dinv,
                                             float* __restrict__ out) {
    const __half2* H2 = (const __half2*)H;
    int wid  = (blockIdx.x * 256 + threadIdx.x) >> 6;
    int lane = threadIdx.x & 63;
    if (wid >= N_NODES) return;
    int i = wid;
    int rs = row_start[i], re = row_start[i + 1];
    float a0 = 0.f, a1 = 0.f;
    int e = rs;
    for (; e + 3 < re; e += 4) {
        int s0 = csr_src[e], s1 = csr_src[e + 1], s2 = csr_src[e + 2], s3 = csr_src[e + 3];
        float d0 = dis[s0], d1 = dis[s1], d2 = dis[s2], d3 = dis[s3];
        float2 h0 = __half22float2(H2[(size_t)s0 * 64 + lane]);
        float2 h1 = __half22float2(H2[(size_t)s1 * 64 + lane]);
        float2 h2 = __half22float2(H2[(size_t)s2 * 64 + lane]);
        float2 h3 = __half22float2(H2[(size_t)s3 * 64 + lane]);
        a0 += d0 * h0.x + d1 * h1.x + d2 * h2.x + d3 * h3.x;
        a1 += d0 * h0.y + d1 * h1.y + d2 * h2.y + d3 * h3.y;
    }
    for (; e < re; e++) {
        int s = csr_src[e];
        float ds = dis[s];
        float2 h = __half22float2(H2[(size_t)s * 64 + lane]);
        a0 += ds * h.x;
        a1 += ds * h.y;
    }
    float di = dis[i], dv = dinv[i];
    float2 hs = __half22float2(H2[(size_t)i * 64 + lane]);
    int c = lane * 2;
    float2 o;
    o.x = a0 * di + dv * hs.x + bias[c];
    o.y = a1 * di + dv * hs.y + bias[c + 1];
    *(float2*)&out[(size_t)i * NF + c] = o;
}

// ---------------------------------------------------------------- pooling
// batch is sorted; block handles 256 contiguous nodes, threads = 2 half-waves
// x 128 features; run-length accumulate, one atomic per (graph-run, feat).
__global__ void k_pool(const float* __restrict__ A, const int* __restrict__ batch,
                       float* __restrict__ sums) {
    int b = blockIdx.x, t = threadIdx.x;
    int c = t & 127, th = t >> 7;
    int start = b * 256 + th;
    if (start >= N_NODES) return;
    int end = min(N_NODES, b * 256 + 256);
    float acc = 0.f;
    int gcur = batch[start];
    for (int i = start; i < end; i += 2) {
        int g = batch[i];
        if (g != gcur) {
            atomicAdd(&sums[gcur * NF + c], acc);
            acc = 0.f;
            gcur = g;
        }
        acc += A[(size_t)i * NF + c];
    }
    atomicAdd(&sums[gcur * NF + c], acc);
}

// ---------------------------------------------------------------- heads
__global__ void k_head(const float* __restrict__ sums, const int* __restrict__ batch,
                       const float* __restrict__ wc, const float* __restrict__ bc,
                       const float* __restrict__ wr, const float* __restrict__ br,
                       float* __restrict__ out) {
    __shared__ float p[128];
    __shared__ int cnt_s;
    int g = blockIdx.x, c = threadIdx.x;
    if (c == 0) {
        int lo = 0, hi = N_NODES;
        while (lo < hi) { int m = (lo + hi) >> 1; if (batch[m] < g) lo = m + 1; else hi = m; }
        int s0 = lo;
        lo = 0; hi = N_NODES;
        while (lo < hi) { int m = (lo + hi) >> 1; if (batch[m] < g + 1) lo = m + 1; else hi = m; }
        cnt_s = lo - s0;
    }
    __syncthreads();
    float cnt = (float)max(cnt_s, 1);
    float pv = sums[g * NF + c] / cnt;
    p[c] = pv;
    out[g * NF + c] = pv;
    __syncthreads();
    if (c < N_CLASSES) {
        float d = bc[c];
        for (int k = 0; k < NF; k++) d += p[k] * wc[k * N_CLASSES + c];
        out[N_GRAPHS * NF + g * N_CLASSES + c] = d;
    }
    if (c == N_CLASSES) {
        float d = br[0];
        for (int k = 0; k < NF; k++) d += p[k] * wr[k];
        out[N_GRAPHS * NF + N_GRAPHS * N_CLASSES + g] = d;
    }
}

// ================================================================= launch
extern "C" void kernel_launch(void* const* d_in, const int* in_sizes, int n_in,
                              void* d_out, int out_size, void* d_ws, size_t ws_size,
                              hipStream_t stream) {
    const float* x     = (const float*)d_in[0];
    const int*   ei    = (const int*)d_in[1];
    const int*   batch = (const int*)d_in[2];
    const float* w0 = (const float*)d_in[3];
    const float* b0 = (const float*)d_in[4];
    const float* w1 = (const float*)d_in[5];
    const float* b1 = (const float*)d_in[6];
    const float* w2 = (const float*)d_in[7];
    const float* b2 = (const float*)d_in[8];
    const float* wc = (const float*)d_in[9];
    const float* bc = (const float*)d_in[10];
    const float* wr = (const float*)d_in[11];
    const float* br = (const float*)d_in[12];
    const int* srcp = ei;
    const int* dstp = ei + N_EDGES;
    float* out = (float*)d_out;

    char* ws = (char*)d_ws;
    size_t off = 0;
    auto alloc = [&](size_t bytes) -> void* {
        void* p = ws + off;
        off = (off + bytes + 255) & ~(size_t)255;
        return p;
    };
    int*    row_start  = (int*)alloc((N_NODES + 1) * 4);
    int*    bucket_cnt = (int*)alloc(NBK * 4);
    int*    bucket_off = (int*)alloc((NBK + 1) * 4);
    int*    bucket_cur = (int*)alloc(NBK * 4);
    float*  dis        = (float*)alloc(N_NODES * 4);
    float*  dinv       = (float*)alloc(N_NODES * 4);
    int*    csr_src    = (int*)alloc((size_t)N_EDGES * 4);
    __half* Hbuf       = (__half*)alloc((size_t)N_NODES * NF * 2);
    float*  Abuf       = (float*)alloc((size_t)N_NODES * NF * 4);
    float*  sums       = (float*)alloc(N_GRAPHS * NF * 4);
    int2*   pairs      = (int2*)alloc((size_t)N_EDGES * 8);  // dead after k_bfill
    (void)ws_size;

    k_zero<<<(N_GRAPHS * NF + 255) / 256, 256, 0, stream>>>(bucket_cnt, sums);
    k_bcount<<<NCHUNKS, 256, 0, stream>>>(dstp, bucket_cnt);
    k_bscan<<<1, 64, 0, stream>>>(bucket_cnt, bucket_off, bucket_cur, row_start);
    k_bscatter<<<NCHUNKS, 256, 0, stream>>>(srcp, dstp, bucket_cur, pairs);
    k_bfill<<<NBK, 256, 0, stream>>>(pairs, bucket_off, row_start, dis, dinv, csr_src);

    const int gemm_grid = (N_NODES + 63) / 64;   // 782
    const int agg_grid  = (N_NODES + 3) / 4;     // 12500

    // layer 0
    k_gemm<false><<<gemm_grid, 256, 0, stream>>>(x, w0, Hbuf);
    k_agg<<<agg_grid, 256, 0, stream>>>(Hbuf, b0, row_start, csr_src, dis, dinv, Abuf);
    // layer 1
    k_gemm<true><<<gemm_grid, 256, 0, stream>>>(Abuf, w1, Hbuf);
    k_agg<<<agg_grid, 256, 0, stream>>>(Hbuf, b1, row_start, csr_src, dis, dinv, Abuf);
    // layer 2
    k_gemm<true><<<gemm_grid, 256, 0, stream>>>(Abuf, w2, Hbuf);
    k_agg<<<agg_grid, 256, 0, stream>>>(Hbuf, b2, row_start, csr_src, dis, dinv, Abuf);

    k_pool<<<(N_NODES + 255) / 256, 256, 0, stream>>>(Abuf, batch, sums);
    k_head<<<N_GRAPHS, 128, 0, stream>>>(sums, batch, wc, bc, wr, br, out);
}

// Round 5
// 468.185 us; speedup vs baseline: 6.1690x; 1.0497x over previous
//
#include <hip/hip_runtime.h>
#include <hip/hip_fp16.h>
#include <math.h>

#define N_NODES   50000
#define N_EDGES   1600000
#define NF        128
#define N_GRAPHS  64
#define N_CLASSES 10

#define NBK       391       // buckets: dst>>7, 128 nodes each (391*128 = 50048)
#define BK_SHIFT  7
#define BK_NODES  128
#define CHUNK     8192
#define NCHUNKS   ((N_EDGES + CHUNK - 1) / CHUNK)   // 196

// ---------------------------------------------------------------- zero init
__global__ void k_zero(int* __restrict__ bucket_cnt, float* __restrict__ sums) {
    int i = blockIdx.x * 256 + threadIdx.x;
    if (i < NBK) bucket_cnt[i] = 0;
    if (i < N_GRAPHS * NF) sums[i] = 0.f;
}

// ------------------------------------------- P1: per-bucket edge histogram
__global__ __launch_bounds__(256) void k_bcount(const int* __restrict__ dst,
                                                int* __restrict__ bucket_cnt) {
    __shared__ int h[NBK];
    int t = threadIdx.x;
    for (int i = t; i < NBK; i += 256) h[i] = 0;
    __syncthreads();
    int base = blockIdx.x * CHUNK;
    int end = min(base + CHUNK, N_EDGES);
    for (int e = base + t; e < end; e += 256)
        atomicAdd(&h[dst[e] >> BK_SHIFT], 1);
    __syncthreads();
    for (int i = t; i < NBK; i += 256)
        if (h[i]) atomicAdd(&bucket_cnt[i], h[i]);
}

// --------------------- P2: parallel scan of the 391 buckets (1 workgroup)
// Round-4 version was a single-thread serial loop: 391 dependent global
// RMWs at ~200-900 cyc each (~100 us hidden cost). LDS Hillis-Steele.
__global__ __launch_bounds__(512) void k_bscan(const int* __restrict__ bucket_cnt,
                                               int* __restrict__ bucket_off,
                                               int* __restrict__ bucket_cursor,
                                               int* __restrict__ row_start) {
    __shared__ int ts[512];
    int t = threadIdx.x;
    int v = (t < NBK) ? bucket_cnt[t] : 0;
    ts[t] = v;
    __syncthreads();
    for (int off = 1; off < 512; off <<= 1) {
        int y = (t >= off) ? ts[t - off] : 0;
        __syncthreads();
        ts[t] += y;
        __syncthreads();
    }
    if (t < NBK) {
        int ex = ts[t] - v;            // exclusive
        bucket_off[t] = ex;
        bucket_cursor[t] = ex;
    }
    if (t == 0) {
        int total = ts[511];           // inclusive over all (>=NBK are 0)
        bucket_off[NBK] = total;       // == N_EDGES
        row_start[N_NODES] = total;
    }
}

// --------------------------- P3: scatter pairs into bucket-grouped storage
// Per-workgroup histogram -> one global reservation per (wg,bucket) -> each
// wg owns contiguous runs, so L2 assembles full lines (round-2's direct
// scatter wrote 101 MB HBM for 6.4 MB payload; this structure fixed it).
__global__ __launch_bounds__(256) void k_bscatter(const int* __restrict__ src,
                                                  const int* __restrict__ dst,
                                                  int* __restrict__ bucket_cursor,
                                                  int2* __restrict__ pairs) {
    __shared__ int h[NBK], rb[NBK], c2[NBK];
    int t = threadIdx.x;
    for (int i = t; i < NBK; i += 256) { h[i] = 0; c2[i] = 0; }
    __syncthreads();
    int base = blockIdx.x * CHUNK;
    int end = min(base + CHUNK, N_EDGES);
    for (int e = base + t; e < end; e += 256)
        atomicAdd(&h[dst[e] >> BK_SHIFT], 1);
    __syncthreads();
    for (int i = t; i < NBK; i += 256)
        rb[i] = h[i] ? atomicAdd(&bucket_cursor[i], h[i]) : 0;
    __syncthreads();
    for (int e = base + t; e < end; e += 256) {
        int d = dst[e];
        int b = d >> BK_SHIFT;
        int k = atomicAdd(&c2[b], 1);
        pairs[rb[b] + k] = make_int2(src[e], d);
    }
}

// ----------------- P4: per-bucket CSR finalize (counts, scan, norms, fill)
__global__ __launch_bounds__(256) void k_bfill(const int2* __restrict__ pairs,
                                               const int* __restrict__ bucket_off,
                                               int* __restrict__ row_start,
                                               float* __restrict__ dis,
                                               int* __restrict__ csr_src) {
    __shared__ int cnt[BK_NODES];
    __shared__ int cur[BK_NODES];
    __shared__ int ts[256];
    int b = blockIdx.x, t = threadIdx.x;
    int node_base = b << BK_SHIFT;
    int lo = bucket_off[b], hi = bucket_off[b + 1];

    if (t < BK_NODES) cnt[t] = 0;
    __syncthreads();
    for (int e = lo + t; e < hi; e += 256)
        atomicAdd(&cnt[pairs[e].y & (BK_NODES - 1)], 1);
    __syncthreads();

    int a = (t < BK_NODES) ? cnt[t] : 0;
    ts[t] = a;
    __syncthreads();
    for (int off = 1; off < 256; off <<= 1) {
        int y = (t >= off) ? ts[t - off] : 0;
        __syncthreads();
        ts[t] += y;
        __syncthreads();
    }
    int row = lo + ts[t] - a;            // exclusive scan
    if (t < BK_NODES) {
        cur[t] = row;
        int n = node_base + t;
        if (n < N_NODES) {
            row_start[n] = row;
            dis[n] = rsqrtf((float)(a + 1));   // deg incl. self-loop
        }
    }
    __syncthreads();

    for (int e = lo + t; e < hi; e += 256) {
        int2 p = pairs[e];
        int pos = atomicAdd(&cur[p.y & (BK_NODES - 1)], 1);
        csr_src[pos] = p.x;
    }
}

// ---------------------------------------------------------------- GEMM
// H'[r][c] = dis[r] * sum_k act(X[r][k]) * W[k][c], fp32 acc, fp16 store.
// Folding dis into H makes k_agg scale-free per edge:
//   agg[i] = dis[i]*(sum_src H'[src] + H'[i]) + b   (self: dis^2 = 1/deg).
// 64 rows x 128 cols per block, thread = 8 rows x 4 cols; x staged in LDS
// (pad 132 breaks stride-128 bank aliasing); w via L1/L2.
// `#pragma unroll 2` + __launch_bounds__(256,4): round-0's full unroll
// spilled (256 VGPR cap, 771 MB scratch writes, 810 us -> 30 us).
template <bool ELU>
__global__ __launch_bounds__(256, 4) void k_gemm(const float* __restrict__ X,
                                                 const float* __restrict__ W,
                                                 const float* __restrict__ dis,
                                                 __half* __restrict__ H) {
    __shared__ float xs[64 * 132];
    int t = threadIdx.x;
    int row0 = blockIdx.x * 64;
#pragma unroll
    for (int i = 0; i < 8; i++) {
        int f = i * 256 + t;          // 0..2047 : 64 rows x 32 float4
        int r = f >> 5, c4 = (f & 31) * 4;
        float4 v = make_float4(0.f, 0.f, 0.f, 0.f);
        if (row0 + r < N_NODES) v = *(const float4*)&X[(size_t)(row0 + r) * NF + c4];
        if (ELU) {
            v.x = v.x > 0.f ? v.x : (expf(v.x) - 1.f);
            v.y = v.y > 0.f ? v.y : (expf(v.y) - 1.f);
            v.z = v.z > 0.f ? v.z : (expf(v.z) - 1.f);
            v.w = v.w > 0.f ? v.w : (expf(v.w) - 1.f);
        }
        *(float4*)&xs[r * 132 + c4] = v;
    }
    __syncthreads();

    int cg = t & 31;   // 4 cols: 4*cg..4*cg+3
    int rg = t >> 5;   // 8 rows: rg*8..rg*8+7
    float acc[8][4] = {};
#pragma unroll 2
    for (int k0 = 0; k0 < NF; k0 += 4) {
        float4 xv[8];
#pragma unroll
        for (int rr = 0; rr < 8; rr++)
            xv[rr] = *(const float4*)&xs[(rg * 8 + rr) * 132 + k0];
#pragma unroll
        for (int kk = 0; kk < 4; kk++) {
            float4 wv = *(const float4*)&W[(k0 + kk) * NF + cg * 4];
#pragma unroll
            for (int rr = 0; rr < 8; rr++) {
                float xk = (kk == 0) ? xv[rr].x : (kk == 1) ? xv[rr].y
                         : (kk == 2) ? xv[rr].z : xv[rr].w;
                acc[rr][0] += xk * wv.x;
                acc[rr][1] += xk * wv.y;
                acc[rr][2] += xk * wv.z;
                acc[rr][3] += xk * wv.w;
            }
        }
    }
#pragma unroll
    for (int rr = 0; rr < 8; rr++) {
        int r = row0 + rg * 8 + rr;
        if (r < N_NODES) {
            float ds = dis[r];
            union { __half2 h2[2]; float2 f2; } u;
            u.h2[0] = __floats2half2_rn(ds * acc[rr][0], ds * acc[rr][1]);
            u.h2[1] = __floats2half2_rn(ds * acc[rr][2], ds * acc[rr][3]);
            *(float2*)&H[(size_t)r * NF + cg * 4] = u.f2;
        }
    }
}

// ------------------------------------------------------------- aggregation
// One wave per node; lane holds features 2*lane, 2*lane+1 (one __half2).
// out[i] = dis[i] * (sum_src H'[src] + H'[i]) + b ; H' = dis (.) H.
// No per-edge dis loads, plain adds in the loop; unroll 8 for MLP.
__global__ __launch_bounds__(256) void k_agg(const __half* __restrict__ H,
                                             const float* __restrict__ bias,
                                             const int* __restrict__ row_start,
                                             const int* __restrict__ csr_src,
                                             const float* __restrict__ dis,
                                             float* __restrict__ out) {
    const __half2* H2 = (const __half2*)H;
    int wid  = (blockIdx.x * 256 + threadIdx.x) >> 6;
    int lane = threadIdx.x & 63;
    if (wid >= N_NODES) return;
    int i = wid;
    int rs = row_start[i], re = row_start[i + 1];
    float a0 = 0.f, a1 = 0.f;
    int e = rs;
    for (; e + 7 < re; e += 8) {
        float2 h[8];
#pragma unroll
        for (int j = 0; j < 8; j++) {
            int s = csr_src[e + j];
            h[j] = __half22float2(H2[(size_t)s * 64 + lane]);
        }
#pragma unroll
        for (int j = 0; j < 8; j++) { a0 += h[j].x; a1 += h[j].y; }
    }
    for (; e < re; e++) {
        int s = csr_src[e];
        float2 h = __half22float2(H2[(size_t)s * 64 + lane]);
        a0 += h.x;
        a1 += h.y;
    }
    float2 hs = __half22float2(H2[(size_t)i * 64 + lane]);
    a0 += hs.x;
    a1 += hs.y;
    float di = dis[i];
    int c = lane * 2;
    float2 o;
    o.x = a0 * di + bias[c];
    o.y = a1 * di + bias[c + 1];
    *(float2*)&out[(size_t)i * NF + c] = o;
}

// ---------------------------------------------------------------- pooling
// batch is sorted; block handles 256 contiguous nodes, threads = 2 half-waves
// x 128 features; run-length accumulate, one atomic per (graph-run, feat).
__global__ void k_pool(const float* __restrict__ A, const int* __restrict__ batch,
                       float* __restrict__ sums) {
    int b = blockIdx.x, t = threadIdx.x;
    int c = t & 127, th = t >> 7;
    int start = b * 256 + th;
    if (start >= N_NODES) return;
    int end = min(N_NODES, b * 256 + 256);
    float acc = 0.f;
    int gcur = batch[start];
    for (int i = start; i < end; i += 2) {
        int g = batch[i];
        if (g != gcur) {
            atomicAdd(&sums[gcur * NF + c], acc);
            acc = 0.f;
            gcur = g;
        }
        acc += A[(size_t)i * NF + c];
    }
    atomicAdd(&sums[gcur * NF + c], acc);
}

// ---------------------------------------------------------------- heads
__global__ void k_head(const float* __restrict__ sums, const int* __restrict__ batch,
                       const float* __restrict__ wc, const float* __restrict__ bc,
                       const float* __restrict__ wr, const float* __restrict__ br,
                       float* __restrict__ out) {
    __shared__ float p[128];
    __shared__ int cnt_s;
    int g = blockIdx.x, c = threadIdx.x;
    if (c == 0) {
        int lo = 0, hi = N_NODES;
        while (lo < hi) { int m = (lo + hi) >> 1; if (batch[m] < g) lo = m + 1; else hi = m; }
        int s0 = lo;
        lo = 0; hi = N_NODES;
        while (lo < hi) { int m = (lo + hi) >> 1; if (batch[m] < g + 1) lo = m + 1; else hi = m; }
        cnt_s = lo - s0;
    }
    __syncthreads();
    float cnt = (float)max(cnt_s, 1);
    float pv = sums[g * NF + c] / cnt;
    p[c] = pv;
    out[g * NF + c] = pv;
    __syncthreads();
    if (c < N_CLASSES) {
        float d = bc[c];
        for (int k = 0; k < NF; k++) d += p[k] * wc[k * N_CLASSES + c];
        out[N_GRAPHS * NF + g * N_CLASSES + c] = d;
    }
    if (c == N_CLASSES) {
        float d = br[0];
        for (int k = 0; k < NF; k++) d += p[k] * wr[k];
        out[N_GRAPHS * NF + N_GRAPHS * N_CLASSES + g] = d;
    }
}

// ================================================================= launch
extern "C" void kernel_launch(void* const* d_in, const int* in_sizes, int n_in,
                              void* d_out, int out_size, void* d_ws, size_t ws_size,
                              hipStream_t stream) {
    const float* x     = (const float*)d_in[0];
    const int*   ei    = (const int*)d_in[1];
    const int*   batch = (const int*)d_in[2];
    const float* w0 = (const float*)d_in[3];
    const float* b0 = (const float*)d_in[4];
    const float* w1 = (const float*)d_in[5];
    const float* b1 = (const float*)d_in[6];
    const float* w2 = (const float*)d_in[7];
    const float* b2 = (const float*)d_in[8];
    const float* wc = (const float*)d_in[9];
    const float* bc = (const float*)d_in[10];
    const float* wr = (const float*)d_in[11];
    const float* br = (const float*)d_in[12];
    const int* srcp = ei;
    const int* dstp = ei + N_EDGES;
    float* out = (float*)d_out;

    char* ws = (char*)d_ws;
    size_t off = 0;
    auto alloc = [&](size_t bytes) -> void* {
        void* p = ws + off;
        off = (off + bytes + 255) & ~(size_t)255;
        return p;
    };
    int*    row_start  = (int*)alloc((N_NODES + 1) * 4);
    int*    bucket_cnt = (int*)alloc(NBK * 4);
    int*    bucket_off = (int*)alloc((NBK + 1) * 4);
    int*    bucket_cur = (int*)alloc(NBK * 4);
    float*  dis        = (float*)alloc(N_NODES * 4);
    int*    csr_src    = (int*)alloc((size_t)N_EDGES * 4);
    __half* Hbuf       = (__half*)alloc((size_t)N_NODES * NF * 2);
    float*  Abuf       = (float*)alloc((size_t)N_NODES * NF * 4);
    float*  sums       = (float*)alloc(N_GRAPHS * NF * 4);
    int2*   pairs      = (int2*)alloc((size_t)N_EDGES * 8);  // dead after k_bfill
    (void)ws_size;

    k_zero<<<(N_GRAPHS * NF + 255) / 256, 256, 0, stream>>>(bucket_cnt, sums);
    k_bcount<<<NCHUNKS, 256, 0, stream>>>(dstp, bucket_cnt);
    k_bscan<<<1, 512, 0, stream>>>(bucket_cnt, bucket_off, bucket_cur, row_start);
    k_bscatter<<<NCHUNKS, 256, 0, stream>>>(srcp, dstp, bucket_cur, pairs);
    k_bfill<<<NBK, 256, 0, stream>>>(pairs, bucket_off, row_start, dis, csr_src);

    const int gemm_grid = (N_NODES + 63) / 64;   // 782
    const int agg_grid  = (N_NODES + 3) / 4;     // 12500

    // layer 0
    k_gemm<false><<<gemm_grid, 256, 0, stream>>>(x, w0, dis, Hbuf);
    k_agg<<<agg_grid, 256, 0, stream>>>(Hbuf, b0, row_start, csr_src, dis, Abuf);
    // layer 1
    k_gemm<true><<<gemm_grid, 256, 0, stream>>>(Abuf, w1, dis, Hbuf);
    k_agg<<<agg_grid, 256, 0, stream>>>(Hbuf, b1, row_start, csr_src, dis, Abuf);
    // layer 2
    k_gemm<true><<<gemm_grid, 256, 0, stream>>>(Abuf, w2, dis, Hbuf);
    k_agg<<<agg_grid, 256, 0, stream>>>(Hbuf, b2, row_start, csr_src, dis, Abuf);

    k_pool<<<(N_NODES + 255) / 256, 256, 0, stream>>>(Abuf, batch, sums);
    k_head<<<N_GRAPHS, 128, 0, stream>>>(sums, batch, wc, bc, wr, br, out);
}

// Round 6
// 430.907 us; speedup vs baseline: 6.7027x; 1.0865x over previous
//
#include <hip/hip_runtime.h>
#include <hip/hip_fp16.h>
#include <math.h>

#define N_NODES   50000
#define N_EDGES   1600000
#define NF        128
#define N_GRAPHS  64
#define N_CLASSES 10

#define NBK       391       // buckets: dst>>7, 128 nodes each (391*128 = 50048)
#define BK_SHIFT  7
#define BK_NODES  128
#define CHUNK     8192
#define NCHUNKS   ((N_EDGES + CHUNK - 1) / CHUNK)   // 196

typedef _Float16 half8 __attribute__((ext_vector_type(8)));
typedef float f32x4 __attribute__((ext_vector_type(4)));

// ---------------------------------------------------------------- zero init
__global__ void k_zero(int* __restrict__ bucket_cnt, float* __restrict__ sums) {
    int i = blockIdx.x * 256 + threadIdx.x;
    if (i < NBK) bucket_cnt[i] = 0;
    if (i < N_GRAPHS * NF) sums[i] = 0.f;
}

// ------------------------------------------- P1: per-bucket edge histogram
__global__ __launch_bounds__(256) void k_bcount(const int* __restrict__ dst,
                                                int* __restrict__ bucket_cnt) {
    __shared__ int h[NBK];
    int t = threadIdx.x;
    for (int i = t; i < NBK; i += 256) h[i] = 0;
    __syncthreads();
    int base = blockIdx.x * CHUNK;
    int end = min(base + CHUNK, N_EDGES);
    for (int e = base + t; e < end; e += 256)
        atomicAdd(&h[dst[e] >> BK_SHIFT], 1);
    __syncthreads();
    for (int i = t; i < NBK; i += 256)
        if (h[i]) atomicAdd(&bucket_cnt[i], h[i]);
}

// --------------------- P2: parallel scan of the 391 buckets (1 workgroup)
__global__ __launch_bounds__(512) void k_bscan(const int* __restrict__ bucket_cnt,
                                               int* __restrict__ bucket_off,
                                               int* __restrict__ bucket_cursor,
                                               int* __restrict__ row_start) {
    __shared__ int ts[512];
    int t = threadIdx.x;
    int v = (t < NBK) ? bucket_cnt[t] : 0;
    ts[t] = v;
    __syncthreads();
    for (int off = 1; off < 512; off <<= 1) {
        int y = (t >= off) ? ts[t - off] : 0;
        __syncthreads();
        ts[t] += y;
        __syncthreads();
    }
    if (t < NBK) {
        int ex = ts[t] - v;            // exclusive
        bucket_off[t] = ex;
        bucket_cursor[t] = ex;
    }
    if (t == 0) {
        int total = ts[511];
        bucket_off[NBK] = total;       // == N_EDGES
        row_start[N_NODES] = total;
    }
}

// ------------- P3: scatter packed (src<<7|dstlocal) into bucket storage
// src<50000 fits 16 bits, local dst 7 bits -> 23-bit pack halves the pairs
// round-trip (was int2). Per-wg reservation keeps writes contiguous (the
// round-2 direct scatter wrote 101 MB HBM for 6.4 MB payload).
__global__ __launch_bounds__(256) void k_bscatter(const int* __restrict__ src,
                                                  const int* __restrict__ dst,
                                                  int* __restrict__ bucket_cursor,
                                                  int* __restrict__ pairs) {
    __shared__ int h[NBK], rb[NBK], c2[NBK];
    int t = threadIdx.x;
    for (int i = t; i < NBK; i += 256) { h[i] = 0; c2[i] = 0; }
    __syncthreads();
    int base = blockIdx.x * CHUNK;
    int end = min(base + CHUNK, N_EDGES);
    for (int e = base + t; e < end; e += 256)
        atomicAdd(&h[dst[e] >> BK_SHIFT], 1);
    __syncthreads();
    for (int i = t; i < NBK; i += 256)
        rb[i] = h[i] ? atomicAdd(&bucket_cursor[i], h[i]) : 0;
    __syncthreads();
    for (int e = base + t; e < end; e += 256) {
        int d = dst[e];
        int b = d >> BK_SHIFT;
        int k = atomicAdd(&c2[b], 1);
        pairs[rb[b] + k] = (src[e] << BK_SHIFT) | (d & (BK_NODES - 1));
    }
}

// ----------------- P4: per-bucket CSR finalize (counts, scan, norms, fill)
__global__ __launch_bounds__(256) void k_bfill(const int* __restrict__ pairs,
                                               const int* __restrict__ bucket_off,
                                               int* __restrict__ row_start,
                                               float* __restrict__ dis,
                                               int* __restrict__ csr_src) {
    __shared__ int cnt[BK_NODES];
    __shared__ int cur[BK_NODES];
    __shared__ int ts[256];
    int b = blockIdx.x, t = threadIdx.x;
    int node_base = b << BK_SHIFT;
    int lo = bucket_off[b], hi = bucket_off[b + 1];

    if (t < BK_NODES) cnt[t] = 0;
    __syncthreads();
    for (int e = lo + t; e < hi; e += 256)
        atomicAdd(&cnt[pairs[e] & (BK_NODES - 1)], 1);
    __syncthreads();

    int a = (t < BK_NODES) ? cnt[t] : 0;
    ts[t] = a;
    __syncthreads();
    for (int off = 1; off < 256; off <<= 1) {
        int y = (t >= off) ? ts[t - off] : 0;
        __syncthreads();
        ts[t] += y;
        __syncthreads();
    }
    int row = lo + ts[t] - a;            // exclusive scan
    if (t < BK_NODES) {
        cur[t] = row;
        int n = node_base + t;
        if (n < N_NODES) {
            row_start[n] = row;
            dis[n] = rsqrtf((float)(a + 1));   // deg incl. self-loop
        }
    }
    __syncthreads();

    for (int e = lo + t; e < hi; e += 256) {
        int p = pairs[e];
        int pos = atomicAdd(&cur[p & (BK_NODES - 1)], 1);
        csr_src[pos] = p >> BK_SHIFT;
    }
}

// ----------------------------------- one-time input/weight fp16 conversion
__global__ void k_xconv(const float* __restrict__ x, _Float16* __restrict__ xh) {
    int i = blockIdx.x * 256 + threadIdx.x;   // float4 index
    if (i >= N_NODES * NF / 4) return;
    float4 v = ((const float4*)x)[i];
    _Float16 h4[4] = {(_Float16)v.x, (_Float16)v.y, (_Float16)v.z, (_Float16)v.w};
    *(uint2*)&xh[(size_t)i * 4] = *(uint2*)h4;
}

// Pre-swizzle W (fp32 [k][n]) into MFMA B-fragment order, fp16:
//   wf[((nt*4+kc)*64 + lane)*8 + j] = W[kc*32 + quad*8 + j][nt*16 + (n&15)]
// so each lane's B-frag is one coalesced 16B load. block b handles matrix b.
__global__ void k_wconv(const float* __restrict__ w0, const float* __restrict__ w1,
                        const float* __restrict__ w2, _Float16* __restrict__ wf) {
    int b = blockIdx.x, t = threadIdx.x;
    const float* W = (b == 0) ? w0 : (b == 1) ? w1 : w2;
    _Float16* dst = wf + (size_t)b * NF * NF;
    for (int idx = t; idx < NF * NF; idx += 256) {
        int k = idx >> 7, n = idx & 127;
        int nt = n >> 4, kc = k >> 5, quad = (k >> 3) & 3, j = k & 7;
        int lane = quad * 16 + (n & 15);
        dst[((nt * 4 + kc) * 64 + lane) * 8 + j] = (_Float16)W[idx];
    }
}

// ------------------------------------------------------------- MFMA GEMM
// H'[r][c] = dis[r] * sum_k act(X[r][k]) * W[k][c]; fp16 in, fp32 acc,
// fp16 out. mfma_f32_16x16x32_f16: A[m=lane&15][k=quad*8+j] from LDS
// (row pad 136 halves: 68-word stride rotates banks by 4/row -> 2-way max,
// free per m136); B-frags pre-swizzled in global (coalesced 16B/lane,
// L2-resident 32KB); C/D: D[row=quad*4+reg][col=lane&15] (m89/m91).
// Block = 4 waves x 16 rows = 64 rows, each wave does 8 n-tiles x 4 k-steps.
template <bool ELU>
__global__ __launch_bounds__(256) void k_gemm(const _Float16* __restrict__ X,
                                              const _Float16* __restrict__ WF,
                                              const float* __restrict__ dis,
                                              __half* __restrict__ H) {
    __shared__ _Float16 xs[64 * 136];
    int t = threadIdx.x;
    int row0 = blockIdx.x * 64;
#pragma unroll
    for (int i = 0; i < 4; i++) {
        int f = i * 256 + t;              // 0..1023 : 64 rows x 16 half8
        int r = f >> 4, c = (f & 15) * 8;
        half8 v = {};
        int gr = row0 + r;
        if (gr < N_NODES) v = *(const half8*)&X[(size_t)gr * NF + c];
        if (ELU) {
#pragma unroll
            for (int j = 0; j < 8; j++) {
                float xv = (float)v[j];
                v[j] = (_Float16)(xv > 0.f ? xv : (expf(xv) - 1.f));
            }
        }
        *(half8*)&xs[r * 136 + c] = v;
    }
    __syncthreads();

    int w = t >> 6;              // wave id: rows w*16..w*16+15
    int lane = t & 63;
    int m = lane & 15, quad = lane >> 4;

    half8 a[4];
#pragma unroll
    for (int kc = 0; kc < 4; kc++)
        a[kc] = *(const half8*)&xs[(w * 16 + m) * 136 + kc * 32 + quad * 8];

    f32x4 acc[8];
#pragma unroll
    for (int nt = 0; nt < 8; nt++) {
        f32x4 c4 = {0.f, 0.f, 0.f, 0.f};
#pragma unroll
        for (int kc = 0; kc < 4; kc++) {
            half8 bf = *(const half8*)&WF[((nt * 4 + kc) * 64 + lane) * 8];
            c4 = __builtin_amdgcn_mfma_f32_16x16x32_f16(a[kc], bf, c4, 0, 0, 0);
        }
        acc[nt] = c4;
    }

#pragma unroll
    for (int reg = 0; reg < 4; reg++) {
        int r = row0 + w * 16 + quad * 4 + reg;
        if (r < N_NODES) {
            float ds = dis[r];
#pragma unroll
            for (int nt = 0; nt < 8; nt++)
                H[(size_t)r * NF + nt * 16 + m] = __float2half(ds * acc[nt][reg]);
        }
    }
}

// ------------------------------------------------------------- aggregation
// One wave per node; lane holds features 2*lane, 2*lane+1 (one __half2).
// out[i] = dis[i] * (sum_src H'[src] + H'[i]) + b ; H' = dis (.) H.
// HALF_OUT: layers 0/1 feed the fp16 GEMM; layer 2 stays fp32 for pooling.
template <bool HALF_OUT>
__global__ __launch_bounds__(256) void k_agg(const __half* __restrict__ H,
                                             const float* __restrict__ bias,
                                             const int* __restrict__ row_start,
                                             const int* __restrict__ csr_src,
                                             const float* __restrict__ dis,
                                             void* __restrict__ outv) {
    const __half2* H2 = (const __half2*)H;
    int wid  = (blockIdx.x * 256 + threadIdx.x) >> 6;
    int lane = threadIdx.x & 63;
    if (wid >= N_NODES) return;
    int i = wid;
    int rs = row_start[i], re = row_start[i + 1];
    float a0 = 0.f, a1 = 0.f;
    int e = rs;
    for (; e + 7 < re; e += 8) {
        float2 h[8];
#pragma unroll
        for (int j = 0; j < 8; j++) {
            int s = csr_src[e + j];
            h[j] = __half22float2(H2[(size_t)s * 64 + lane]);
        }
#pragma unroll
        for (int j = 0; j < 8; j++) { a0 += h[j].x; a1 += h[j].y; }
    }
    for (; e < re; e++) {
        int s = csr_src[e];
        float2 h = __half22float2(H2[(size_t)s * 64 + lane]);
        a0 += h.x;
        a1 += h.y;
    }
    float2 hs = __half22float2(H2[(size_t)i * 64 + lane]);
    a0 += hs.x;
    a1 += hs.y;
    float di = dis[i];
    int c = lane * 2;
    float o0 = a0 * di + bias[c];
    float o1 = a1 * di + bias[c + 1];
    if (HALF_OUT) {
        ((__half2*)outv)[(size_t)i * 64 + lane] = __floats2half2_rn(o0, o1);
    } else {
        float2 o = make_float2(o0, o1);
        *(float2*)&((float*)outv)[(size_t)i * NF + c] = o;
    }
}

// ---------------------------------------------------------------- pooling
__global__ void k_pool(const float* __restrict__ A, const int* __restrict__ batch,
                       float* __restrict__ sums) {
    int b = blockIdx.x, t = threadIdx.x;
    int c = t & 127, th = t >> 7;
    int start = b * 256 + th;
    if (start >= N_NODES) return;
    int end = min(N_NODES, b * 256 + 256);
    float acc = 0.f;
    int gcur = batch[start];
    for (int i = start; i < end; i += 2) {
        int g = batch[i];
        if (g != gcur) {
            atomicAdd(&sums[gcur * NF + c], acc);
            acc = 0.f;
            gcur = g;
        }
        acc += A[(size_t)i * NF + c];
    }
    atomicAdd(&sums[gcur * NF + c], acc);
}

// ---------------------------------------------------------------- heads
__global__ void k_head(const float* __restrict__ sums, const int* __restrict__ batch,
                       const float* __restrict__ wc, const float* __restrict__ bc,
                       const float* __restrict__ wr, const float* __restrict__ br,
                       float* __restrict__ out) {
    __shared__ float p[128];
    __shared__ int cnt_s;
    int g = blockIdx.x, c = threadIdx.x;
    if (c == 0) {
        int lo = 0, hi = N_NODES;
        while (lo < hi) { int m = (lo + hi) >> 1; if (batch[m] < g) lo = m + 1; else hi = m; }
        int s0 = lo;
        lo = 0; hi = N_NODES;
        while (lo < hi) { int m = (lo + hi) >> 1; if (batch[m] < g + 1) lo = m + 1; else hi = m; }
        cnt_s = lo - s0;
    }
    __syncthreads();
    float cnt = (float)max(cnt_s, 1);
    float pv = sums[g * NF + c] / cnt;
    p[c] = pv;
    out[g * NF + c] = pv;
    __syncthreads();
    if (c < N_CLASSES) {
        float d = bc[c];
        for (int k = 0; k < NF; k++) d += p[k] * wc[k * N_CLASSES + c];
        out[N_GRAPHS * NF + g * N_CLASSES + c] = d;
    }
    if (c == N_CLASSES) {
        float d = br[0];
        for (int k = 0; k < NF; k++) d += p[k] * wr[k];
        out[N_GRAPHS * NF + N_GRAPHS * N_CLASSES + g] = d;
    }
}

// ================================================================= launch
extern "C" void kernel_launch(void* const* d_in, const int* in_sizes, int n_in,
                              void* d_out, int out_size, void* d_ws, size_t ws_size,
                              hipStream_t stream) {
    const float* x     = (const float*)d_in[0];
    const int*   ei    = (const int*)d_in[1];
    const int*   batch = (const int*)d_in[2];
    const float* w0 = (const float*)d_in[3];
    const float* b0 = (const float*)d_in[4];
    const float* w1 = (const float*)d_in[5];
    const float* b1 = (const float*)d_in[6];
    const float* w2 = (const float*)d_in[7];
    const float* b2 = (const float*)d_in[8];
    const float* wc = (const float*)d_in[9];
    const float* bc = (const float*)d_in[10];
    const float* wr = (const float*)d_in[11];
    const float* br = (const float*)d_in[12];
    const int* srcp = ei;
    const int* dstp = ei + N_EDGES;
    float* out = (float*)d_out;

    char* ws = (char*)d_ws;
    size_t off = 0;
    auto alloc = [&](size_t bytes) -> void* {
        void* p = ws + off;
        off = (off + bytes + 255) & ~(size_t)255;
        return p;
    };
    const int NPAD = N_NODES + 64;
    int*      row_start  = (int*)alloc((N_NODES + 1) * 4);
    int*      bucket_cnt = (int*)alloc(NBK * 4);
    int*      bucket_off = (int*)alloc((NBK + 1) * 4);
    int*      bucket_cur = (int*)alloc(NBK * 4);
    float*    dis        = (float*)alloc(N_NODES * 4);
    int*      csr_src    = (int*)alloc((size_t)N_EDGES * 4);
    __half*   Hbuf       = (__half*)alloc((size_t)NPAD * NF * 2);
    float*    Abuf       = (float*)alloc((size_t)NPAD * NF * 4);
    _Float16* xh         = (_Float16*)alloc((size_t)NPAD * NF * 2);
    _Float16* wf         = (_Float16*)alloc((size_t)3 * NF * NF * 2);
    float*    sums       = (float*)alloc(N_GRAPHS * NF * 4);
    (void)ws_size;
    // pairs (6.4 MB, packed) aliases Abuf (dead after k_bfill; Abuf first
    // written by layer-2 agg). xh doubles as Ah: dead after gemm0 reads it,
    // then agg0/agg1 write their fp16 output there.
    int* pairs = (int*)Abuf;
    _Float16* Ah = xh;

    k_zero<<<(N_GRAPHS * NF + 255) / 256, 256, 0, stream>>>(bucket_cnt, sums);
    k_bcount<<<NCHUNKS, 256, 0, stream>>>(dstp, bucket_cnt);
    k_bscan<<<1, 512, 0, stream>>>(bucket_cnt, bucket_off, bucket_cur, row_start);
    k_bscatter<<<NCHUNKS, 256, 0, stream>>>(srcp, dstp, bucket_cur, pairs);
    k_bfill<<<NBK, 256, 0, stream>>>(pairs, bucket_off, row_start, dis, csr_src);
    k_wconv<<<3, 256, 0, stream>>>(w0, w1, w2, wf);
    k_xconv<<<(N_NODES * NF / 4 + 255) / 256, 256, 0, stream>>>(x, xh);

    const int gemm_grid = (N_NODES + 63) / 64;   // 782
    const int agg_grid  = (N_NODES + 3) / 4;     // 12500

    // layer 0 (xh consumed by gemm0, then reused as Ah)
    k_gemm<false><<<gemm_grid, 256, 0, stream>>>(xh, wf, dis, Hbuf);
    k_agg<true><<<agg_grid, 256, 0, stream>>>(Hbuf, b0, row_start, csr_src, dis, Ah);
    // layer 1
    k_gemm<true><<<gemm_grid, 256, 0, stream>>>(Ah, wf + NF * NF, dis, Hbuf);
    k_agg<true><<<agg_grid, 256, 0, stream>>>(Hbuf, b1, row_start, csr_src, dis, Ah);
    // layer 2
    k_gemm<true><<<gemm_grid, 256, 0, stream>>>(Ah, wf + 2 * NF * NF, dis, Hbuf);
    k_agg<false><<<agg_grid, 256, 0, stream>>>(Hbuf, b2, row_start, csr_src, dis, Abuf);

    k_pool<<<(N_NODES + 255) / 256, 256, 0, stream>>>(Abuf, batch, sums);
    k_head<<<N_GRAPHS, 128, 0, stream>>>(sums, batch, wc, bc, wr, br, out);
}

// Round 7
// 404.462 us; speedup vs baseline: 7.1410x; 1.0654x over previous
//
#include <hip/hip_runtime.h>
#include <hip/hip_fp16.h>
#include <math.h>

#define N_NODES   50000
#define N_EDGES   1600000
#define NF        128
#define N_GRAPHS  64
#define N_CLASSES 10

#define NBK       391       // buckets: dst>>7, 128 nodes each (391*128 = 50048)
#define BK_SHIFT  7
#define BK_NODES  128
#define SLAB      5120      // slab capacity/bucket: mean 4096, sigma~64, +16s
#define CHUNK     4096
#define NCHUNKS   ((N_EDGES + CHUNK - 1) / CHUNK)   // 391

typedef _Float16 half8 __attribute__((ext_vector_type(8)));
typedef float f32x4 __attribute__((ext_vector_type(4)));

// ------------------------------------------------------------ zero / init
// bucket_cursor[b] = b*SLAB (static slab bases: no count/scan prepass).
__global__ void k_zero(int* __restrict__ bucket_cur, float* __restrict__ sums) {
    int i = blockIdx.x * 256 + threadIdx.x;
    if (i < NBK) bucket_cur[i] = i * SLAB;
    if (i < N_GRAPHS * NF) sums[i] = 0.f;
}

// ------------- P1: scatter packed (src<<7|dstlocal) into bucket slabs
// Per-wg LDS histogram -> one global reservation per (wg,bucket) -> each wg
// owns contiguous runs (round-2's direct scatter wrote 101 MB HBM for
// 6.4 MB payload; reservation keeps L2 lines whole). 391 wgs for occupancy.
__global__ __launch_bounds__(256) void k_bscatter(const int* __restrict__ src,
                                                  const int* __restrict__ dst,
                                                  int* __restrict__ bucket_cur,
                                                  int* __restrict__ pairs) {
    __shared__ int h[NBK], rb[NBK], c2[NBK];
    int t = threadIdx.x;
    for (int i = t; i < NBK; i += 256) { h[i] = 0; c2[i] = 0; }
    __syncthreads();
    int base = blockIdx.x * CHUNK;
    int end = min(base + CHUNK, N_EDGES);
    for (int e = base + t; e < end; e += 256)
        atomicAdd(&h[dst[e] >> BK_SHIFT], 1);
    __syncthreads();
    for (int i = t; i < NBK; i += 256)
        rb[i] = h[i] ? atomicAdd(&bucket_cur[i], h[i]) : 0;
    __syncthreads();
    for (int e = base + t; e < end; e += 256) {
        int d = dst[e];
        int b = d >> BK_SHIFT;
        int k = atomicAdd(&c2[b], 1);
        pairs[rb[b] + k] = (src[e] << BK_SHIFT) | (d & (BK_NODES - 1));
    }
}

// ----------------- P2: per-bucket CSR finalize (counts, scan, norms, fill)
// One 512-thread wg per bucket; csr_src lives in the same slab layout, so
// row ranges are [row_start[n], row_end[n]) inside slab b.
__global__ __launch_bounds__(512) void k_bfill(const int* __restrict__ pairs,
                                               const int* __restrict__ bucket_cur,
                                               int* __restrict__ row_start,
                                               int* __restrict__ row_end,
                                               float* __restrict__ dis,
                                               int* __restrict__ csr_src) {
    __shared__ int cnt[BK_NODES];
    __shared__ int cur[BK_NODES];
    __shared__ int ts[512];
    int b = blockIdx.x, t = threadIdx.x;
    int node_base = b << BK_SHIFT;
    int lo = b * SLAB, hi = bucket_cur[b];

    if (t < BK_NODES) cnt[t] = 0;
    __syncthreads();
    for (int e = lo + t; e < hi; e += 512)
        atomicAdd(&cnt[pairs[e] & (BK_NODES - 1)], 1);
    __syncthreads();

    int a = (t < BK_NODES) ? cnt[t] : 0;
    ts[t] = a;
    __syncthreads();
    for (int off = 1; off < BK_NODES; off <<= 1) {   // scan first 128 entries
        int y = (t >= off) ? ts[t - off] : 0;
        __syncthreads();
        ts[t] += y;
        __syncthreads();
    }
    int row = lo + ts[t] - a;            // exclusive scan within slab
    if (t < BK_NODES) {
        cur[t] = row;
        int n = node_base + t;
        if (n < N_NODES) {
            row_start[n] = row;
            row_end[n]   = row + a;
            dis[n] = rsqrtf((float)(a + 1));   // deg incl. self-loop
        }
    }
    __syncthreads();

    for (int e = lo + t; e < hi; e += 512) {
        int p = pairs[e];
        int pos = atomicAdd(&cur[p & (BK_NODES - 1)], 1);
        csr_src[pos] = p >> BK_SHIFT;
    }
}

// ----------------------------------- one-time input/weight fp16 conversion
__global__ void k_xconv(const float* __restrict__ x, _Float16* __restrict__ xh) {
    int i = blockIdx.x * 256 + threadIdx.x;   // float4 index
    if (i >= N_NODES * NF / 4) return;
    float4 v = ((const float4*)x)[i];
    _Float16 h4[4] = {(_Float16)v.x, (_Float16)v.y, (_Float16)v.z, (_Float16)v.w};
    *(uint2*)&xh[(size_t)i * 4] = *(uint2*)h4;
}

// Pre-swizzle W (fp32 [k][n]) into MFMA B-fragment order, fp16:
//   wf[((nt*4+kc)*64 + lane)*8 + j] = W[kc*32 + quad*8 + j][nt*16 + (n&15)]
__global__ void k_wconv(const float* __restrict__ w0, const float* __restrict__ w1,
                        const float* __restrict__ w2, _Float16* __restrict__ wf) {
    int b = blockIdx.x, t = threadIdx.x;
    const float* W = (b == 0) ? w0 : (b == 1) ? w1 : w2;
    _Float16* dst = wf + (size_t)b * NF * NF;
    for (int idx = t; idx < NF * NF; idx += 256) {
        int k = idx >> 7, n = idx & 127;
        int nt = n >> 4, kc = k >> 5, quad = (k >> 3) & 3, j = k & 7;
        int lane = quad * 16 + (n & 15);
        dst[((nt * 4 + kc) * 64 + lane) * 8 + j] = (_Float16)W[idx];
    }
}

// ------------------------------------------------------------- MFMA GEMM
// H'[r][c] = dis[r] * sum_k act(X[r][k]) * W[k][c]; fp16 in, fp32 acc,
// fp16 out. mfma_f32_16x16x32_f16: A[m=lane&15][k=quad*8+j] from LDS
// (pad 136); B-frags pre-swizzled in global (coalesced 16B/lane, L2-hot);
// C/D: D[row=quad*4+reg][col=lane&15] (m89/m91).
template <bool ELU>
__global__ __launch_bounds__(256) void k_gemm(const _Float16* __restrict__ X,
                                              const _Float16* __restrict__ WF,
                                              const float* __restrict__ dis,
                                              __half* __restrict__ H) {
    __shared__ _Float16 xs[64 * 136];
    int t = threadIdx.x;
    int row0 = blockIdx.x * 64;
#pragma unroll
    for (int i = 0; i < 4; i++) {
        int f = i * 256 + t;              // 0..1023 : 64 rows x 16 half8
        int r = f >> 4, c = (f & 15) * 8;
        half8 v = {};
        int gr = row0 + r;
        if (gr < N_NODES) v = *(const half8*)&X[(size_t)gr * NF + c];
        if (ELU) {
#pragma unroll
            for (int j = 0; j < 8; j++) {
                float xv = (float)v[j];
                v[j] = (_Float16)(xv > 0.f ? xv : (expf(xv) - 1.f));
            }
        }
        *(half8*)&xs[r * 136 + c] = v;
    }
    __syncthreads();

    int w = t >> 6;              // wave id: rows w*16..w*16+15
    int lane = t & 63;
    int m = lane & 15, quad = lane >> 4;

    half8 a[4];
#pragma unroll
    for (int kc = 0; kc < 4; kc++)
        a[kc] = *(const half8*)&xs[(w * 16 + m) * 136 + kc * 32 + quad * 8];

    f32x4 acc[8];
#pragma unroll
    for (int nt = 0; nt < 8; nt++) {
        f32x4 c4 = {0.f, 0.f, 0.f, 0.f};
#pragma unroll
        for (int kc = 0; kc < 4; kc++) {
            half8 bf = *(const half8*)&WF[((nt * 4 + kc) * 64 + lane) * 8];
            c4 = __builtin_amdgcn_mfma_f32_16x16x32_f16(a[kc], bf, c4, 0, 0, 0);
        }
        acc[nt] = c4;
    }

#pragma unroll
    for (int reg = 0; reg < 4; reg++) {
        int r = row0 + w * 16 + quad * 4 + reg;
        if (r < N_NODES) {
            float ds = dis[r];
#pragma unroll
            for (int nt = 0; nt < 8; nt++)
                H[(size_t)r * NF + nt * 16 + m] = __float2half(ds * acc[nt][reg]);
        }
    }
}

// ------------------------------------------------------------- aggregation
// 2 nodes per wave: 32 lanes x 8 B (4 halves) per row -> one load instr
// fetches 8 cache lines (2 rows) vs 4 before; per-edge VALU/issue overhead
// halves. out[i] = dis[i]*(sum_src H'[src] + H'[i]) + b ; H' = dis (.) H.
template <bool HALF_OUT>
__global__ __launch_bounds__(256) void k_agg(const __half* __restrict__ H,
                                             const float* __restrict__ bias,
                                             const int* __restrict__ row_start,
                                             const int* __restrict__ row_end,
                                             const int* __restrict__ csr_src,
                                             const float* __restrict__ dis,
                                             void* __restrict__ outv) {
    const uint2* H4 = (const uint2*)H;      // 8 B = 4 halves; row stride 32
    int wv   = (blockIdx.x * 256 + threadIdx.x) >> 6;
    int lane = threadIdx.x & 63;
    int node = wv * 2 + (lane >> 5);        // grid covers exactly N_NODES
    int l    = lane & 31;
    if (node >= N_NODES) return;
    int rs = row_start[node], re = row_end[node];
    float a0 = 0.f, a1 = 0.f, a2 = 0.f, a3 = 0.f;
    int e = rs;
    for (; e + 7 < re; e += 8) {
        uint2 v[8];
#pragma unroll
        for (int j = 0; j < 8; j++) {
            int s = csr_src[e + j];
            v[j] = H4[(size_t)s * 32 + l];
        }
#pragma unroll
        for (int j = 0; j < 8; j++) {
            float2 lo = __half22float2(*(__half2*)&v[j].x);
            float2 hi = __half22float2(*(__half2*)&v[j].y);
            a0 += lo.x; a1 += lo.y; a2 += hi.x; a3 += hi.y;
        }
    }
    for (; e < re; e++) {
        int s = csr_src[e];
        uint2 v = H4[(size_t)s * 32 + l];
        float2 lo = __half22float2(*(__half2*)&v.x);
        float2 hi = __half22float2(*(__half2*)&v.y);
        a0 += lo.x; a1 += lo.y; a2 += hi.x; a3 += hi.y;
    }
    {
        uint2 v = H4[(size_t)node * 32 + l];     // self-loop term
        float2 lo = __half22float2(*(__half2*)&v.x);
        float2 hi = __half22float2(*(__half2*)&v.y);
        a0 += lo.x; a1 += lo.y; a2 += hi.x; a3 += hi.y;
    }
    float di = dis[node];
    int c = l * 4;
    float4 bv = *(const float4*)&bias[c];
    float o0 = a0 * di + bv.x, o1 = a1 * di + bv.y;
    float o2 = a2 * di + bv.z, o3 = a3 * di + bv.w;
    if (HALF_OUT) {
        uint2 o;
        *(__half2*)&o.x = __floats2half2_rn(o0, o1);
        *(__half2*)&o.y = __floats2half2_rn(o2, o3);
        ((uint2*)outv)[(size_t)node * 32 + l] = o;
    } else {
        *(float4*)&((float*)outv)[(size_t)node * NF + c] = make_float4(o0, o1, o2, o3);
    }
}

// ---------------------------------------------------------------- pooling
// batch is sorted; block handles 256 contiguous nodes, threads = 2 half-waves
// x 128 features; run-length accumulate, one atomic per (graph-run, feat).
__global__ void k_pool(const float* __restrict__ A, const int* __restrict__ batch,
                       float* __restrict__ sums) {
    int b = blockIdx.x, t = threadIdx.x;
    int c = t & 127, th = t >> 7;
    int start = b * 256 + th;
    if (start >= N_NODES) return;
    int end = min(N_NODES, b * 256 + 256);
    float acc = 0.f;
    int gcur = batch[start];
    for (int i = start; i < end; i += 2) {
        int g = batch[i];
        if (g != gcur) {
            atomicAdd(&sums[gcur * NF + c], acc);
            acc = 0.f;
            gcur = g;
        }
        acc += A[(size_t)i * NF + c];
    }
    atomicAdd(&sums[gcur * NF + c], acc);
}

// ---------------------------------------------------------------- heads
__global__ void k_head(const float* __restrict__ sums, const int* __restrict__ batch,
                       const float* __restrict__ wc, const float* __restrict__ bc,
                       const float* __restrict__ wr, const float* __restrict__ br,
                       float* __restrict__ out) {
    __shared__ float p[128];
    __shared__ int cnt_s;
    int g = blockIdx.x, c = threadIdx.x;
    if (c == 0) {
        int lo = 0, hi = N_NODES;
        while (lo < hi) { int m = (lo + hi) >> 1; if (batch[m] < g) lo = m + 1; else hi = m; }
        int s0 = lo;
        lo = 0; hi = N_NODES;
        while (lo < hi) { int m = (lo + hi) >> 1; if (batch[m] < g + 1) lo = m + 1; else hi = m; }
        cnt_s = lo - s0;
    }
    __syncthreads();
    float cnt = (float)max(cnt_s, 1);
    float pv = sums[g * NF + c] / cnt;
    p[c] = pv;
    out[g * NF + c] = pv;
    __syncthreads();
    if (c < N_CLASSES) {
        float d = bc[c];
        for (int k = 0; k < NF; k++) d += p[k] * wc[k * N_CLASSES + c];
        out[N_GRAPHS * NF + g * N_CLASSES + c] = d;
    }
    if (c == N_CLASSES) {
        float d = br[0];
        for (int k = 0; k < NF; k++) d += p[k] * wr[k];
        out[N_GRAPHS * NF + N_GRAPHS * N_CLASSES + g] = d;
    }
}

// ================================================================= launch
extern "C" void kernel_launch(void* const* d_in, const int* in_sizes, int n_in,
                              void* d_out, int out_size, void* d_ws, size_t ws_size,
                              hipStream_t stream) {
    const float* x     = (const float*)d_in[0];
    const int*   ei    = (const int*)d_in[1];
    const int*   batch = (const int*)d_in[2];
    const float* w0 = (const float*)d_in[3];
    const float* b0 = (const float*)d_in[4];
    const float* w1 = (const float*)d_in[5];
    const float* b1 = (const float*)d_in[6];
    const float* w2 = (const float*)d_in[7];
    const float* b2 = (const float*)d_in[8];
    const float* wc = (const float*)d_in[9];
    const float* bc = (const float*)d_in[10];
    const float* wr = (const float*)d_in[11];
    const float* br = (const float*)d_in[12];
    const int* srcp = ei;
    const int* dstp = ei + N_EDGES;
    float* out = (float*)d_out;

    char* ws = (char*)d_ws;
    size_t off = 0;
    auto alloc = [&](size_t bytes) -> void* {
        void* p = ws + off;
        off = (off + bytes + 255) & ~(size_t)255;
        return p;
    };
    const int NPAD = N_NODES + 64;
    int*      row_start  = (int*)alloc(N_NODES * 4);
    int*      row_end    = (int*)alloc(N_NODES * 4);
    int*      bucket_cur = (int*)alloc(NBK * 4);
    float*    dis        = (float*)alloc(N_NODES * 4);
    int*      csr_src    = (int*)alloc((size_t)NBK * SLAB * 4);   // slab layout
    __half*   Hbuf       = (__half*)alloc((size_t)NPAD * NF * 2);
    float*    Abuf       = (float*)alloc((size_t)NPAD * NF * 4);
    _Float16* xh         = (_Float16*)alloc((size_t)NPAD * NF * 2);
    _Float16* wf         = (_Float16*)alloc((size_t)3 * NF * NF * 2);
    float*    sums       = (float*)alloc(N_GRAPHS * NF * 4);
    (void)ws_size;
    // pairs (8 MB slab) aliases Abuf (25.6 MB): dead after k_bfill; Abuf is
    // first written by layer-2 agg. xh doubles as Ah (dead after gemm0).
    int* pairs = (int*)Abuf;
    _Float16* Ah = xh;

    k_zero<<<32, 256, 0, stream>>>(bucket_cur, sums);
    k_bscatter<<<NCHUNKS, 256, 0, stream>>>(srcp, dstp, bucket_cur, pairs);
    k_bfill<<<NBK, 512, 0, stream>>>(pairs, bucket_cur, row_start, row_end, dis, csr_src);
    k_wconv<<<3, 256, 0, stream>>>(w0, w1, w2, wf);
    k_xconv<<<(N_NODES * NF / 4 + 255) / 256, 256, 0, stream>>>(x, xh);

    const int gemm_grid = (N_NODES + 63) / 64;   // 782
    const int agg_grid  = (N_NODES + 7) / 8;     // 6250 (8 nodes/block)

    // layer 0 (xh consumed by gemm0, then reused as Ah)
    k_gemm<false><<<gemm_grid, 256, 0, stream>>>(xh, wf, dis, Hbuf);
    k_agg<true><<<agg_grid, 256, 0, stream>>>(Hbuf, b0, row_start, row_end, csr_src, dis, Ah);
    // layer 1
    k_gemm<true><<<gemm_grid, 256, 0, stream>>>(Ah, wf + NF * NF, dis, Hbuf);
    k_agg<true><<<agg_grid, 256, 0, stream>>>(Hbuf, b1, row_start, row_end, csr_src, dis, Ah);
    // layer 2
    k_gemm<true><<<gemm_grid, 256, 0, stream>>>(Ah, wf + 2 * NF * NF, dis, Hbuf);
    k_agg<false><<<agg_grid, 256, 0, stream>>>(Hbuf, b2, row_start, row_end, csr_src, dis, Abuf);

    k_pool<<<(N_NODES + 255) / 256, 256, 0, stream>>>(Abuf, batch, sums);
    k_head<<<N_GRAPHS, 128, 0, stream>>>(sums, batch, wc, bc, wr, br, out);
}

// Round 8
// 375.711 us; speedup vs baseline: 7.6874x; 1.0765x over previous
//
#include <hip/hip_runtime.h>
#include <hip/hip_fp16.h>
#include <math.h>

#define N_NODES   50000
#define N_EDGES   1600000
#define NF        128
#define N_GRAPHS  64
#define N_CLASSES 10

#define NBK       391       // buckets: dst>>7, 128 nodes each (391*128 = 50048)
#define BK_SHIFT  7
#define BK_NODES  128
#define SLAB      5120      // slab capacity/bucket: mean 4096, sigma~64, +16s
#define CHUNK     4096
#define NCHUNKS   ((N_EDGES + CHUNK - 1) / CHUNK)   // 391

typedef _Float16 half8 __attribute__((ext_vector_type(8)));
typedef float f32x4 __attribute__((ext_vector_type(4)));

// ------------------------------------------------------------ zero / init
// bucket_cursor[b] = b*SLAB (static slab bases: no count/scan prepass).
__global__ void k_zero(int* __restrict__ bucket_cur, float* __restrict__ sums) {
    int i = blockIdx.x * 256 + threadIdx.x;
    if (i < NBK) bucket_cur[i] = i * SLAB;
    if (i < N_GRAPHS * NF) sums[i] = 0.f;
}

// ------------- P1: scatter packed (src<<7|dstlocal) into bucket slabs
// Per-wg LDS histogram -> one global reservation per (wg,bucket) -> each wg
// owns contiguous runs (round-2's direct scatter wrote 101 MB HBM for
// 6.4 MB payload; reservation keeps L2 lines whole).
__global__ __launch_bounds__(256) void k_bscatter(const int* __restrict__ src,
                                                  const int* __restrict__ dst,
                                                  int* __restrict__ bucket_cur,
                                                  int* __restrict__ pairs) {
    __shared__ int h[NBK], rb[NBK], c2[NBK];
    int t = threadIdx.x;
    for (int i = t; i < NBK; i += 256) { h[i] = 0; c2[i] = 0; }
    __syncthreads();
    int base = blockIdx.x * CHUNK;
    int end = min(base + CHUNK, N_EDGES);
    for (int e = base + t; e < end; e += 256)
        atomicAdd(&h[dst[e] >> BK_SHIFT], 1);
    __syncthreads();
    for (int i = t; i < NBK; i += 256)
        rb[i] = h[i] ? atomicAdd(&bucket_cur[i], h[i]) : 0;
    __syncthreads();
    for (int e = base + t; e < end; e += 256) {
        int d = dst[e];
        int b = d >> BK_SHIFT;
        int k = atomicAdd(&c2[b], 1);
        pairs[rb[b] + k] = (src[e] << BK_SHIFT) | (d & (BK_NODES - 1));
    }
}

// ----------------- P2: per-bucket CSR finalize (counts, scan, norms, fill)
__global__ __launch_bounds__(512) void k_bfill(const int* __restrict__ pairs,
                                               const int* __restrict__ bucket_cur,
                                               int* __restrict__ row_start,
                                               int* __restrict__ row_end,
                                               float* __restrict__ dis,
                                               int* __restrict__ csr_src) {
    __shared__ int cnt[BK_NODES];
    __shared__ int cur[BK_NODES];
    __shared__ int ts[512];
    int b = blockIdx.x, t = threadIdx.x;
    int node_base = b << BK_SHIFT;
    int lo = b * SLAB, hi = bucket_cur[b];

    if (t < BK_NODES) cnt[t] = 0;
    __syncthreads();
    for (int e = lo + t; e < hi; e += 512)
        atomicAdd(&cnt[pairs[e] & (BK_NODES - 1)], 1);
    __syncthreads();

    int a = (t < BK_NODES) ? cnt[t] : 0;
    ts[t] = a;
    __syncthreads();
    for (int off = 1; off < BK_NODES; off <<= 1) {
        int y = (t >= off) ? ts[t - off] : 0;
        __syncthreads();
        ts[t] += y;
        __syncthreads();
    }
    int row = lo + ts[t] - a;            // exclusive scan within slab
    if (t < BK_NODES) {
        cur[t] = row;
        int n = node_base + t;
        if (n < N_NODES) {
            row_start[n] = row;
            row_end[n]   = row + a;
            dis[n] = rsqrtf((float)(a + 1));   // deg incl. self-loop
        }
    }
    __syncthreads();

    for (int e = lo + t; e < hi; e += 512) {
        int p = pairs[e];
        int pos = atomicAdd(&cur[p & (BK_NODES - 1)], 1);
        csr_src[pos] = p >> BK_SHIFT;
    }
}

// Pre-swizzle W (fp32 [k][n]) into MFMA B-fragment order, fp16:
//   wf[((nt*4+kc)*64 + lane)*8 + j] = W[kc*32 + quad*8 + j][nt*16 + (n&15)]
__global__ void k_wconv(const float* __restrict__ w0, const float* __restrict__ w1,
                        const float* __restrict__ w2, _Float16* __restrict__ wf) {
    int b = blockIdx.x, t = threadIdx.x;
    const float* W = (b == 0) ? w0 : (b == 1) ? w1 : w2;
    _Float16* dst = wf + (size_t)b * NF * NF;
    for (int idx = t; idx < NF * NF; idx += 256) {
        int k = idx >> 7, n = idx & 127;
        int nt = n >> 4, kc = k >> 5, quad = (k >> 3) & 3, j = k & 7;
        int lane = quad * 16 + (n & 15);
        dst[((nt * 4 + kc) * 64 + lane) * 8 + j] = (_Float16)W[idx];
    }
}

// ------------------------------------------------------------- MFMA GEMM
// H'[r][c] = dis[r] * sum_k act(X[r][k]) * W[k][c]; fp32 acc, fp16 out.
// FP32IN: layer 0 reads x fp32 directly (deletes the separate 38 MB
// k_xconv round-trip). mfma_f32_16x16x32_f16: A[m=lane&15][k=quad*8+j]
// from LDS (pad 136); B-frags pre-swizzled (coalesced 16B/lane, L2-hot);
// C/D: D[row=quad*4+reg][col=lane&15] (m89/m91). Epilogue: round-7 did 32
// scalar 2B global stores/thread (col stride 16 per lane); now LDS
// transpose -> 4x coalesced half8 stores.
template <bool ELU, bool FP32IN>
__global__ __launch_bounds__(256) void k_gemm(const void* __restrict__ Xv,
                                              const _Float16* __restrict__ WF,
                                              const float* __restrict__ dis,
                                              __half* __restrict__ H) {
    __shared__ _Float16 xs[64 * 136];
    const _Float16* Xh = (const _Float16*)Xv;
    const float*    Xf = (const float*)Xv;
    int t = threadIdx.x;
    int row0 = blockIdx.x * 64;
#pragma unroll
    for (int i = 0; i < 4; i++) {
        int f = i * 256 + t;              // 0..1023 : 64 rows x 16 half8
        int r = f >> 4, c = (f & 15) * 8;
        int gr = row0 + r;
        half8 v = {};
        if (gr < N_NODES) {
            if (FP32IN) {
                float4 v0 = *(const float4*)&Xf[(size_t)gr * NF + c];
                float4 v1 = *(const float4*)&Xf[(size_t)gr * NF + c + 4];
                v[0] = (_Float16)v0.x; v[1] = (_Float16)v0.y;
                v[2] = (_Float16)v0.z; v[3] = (_Float16)v0.w;
                v[4] = (_Float16)v1.x; v[5] = (_Float16)v1.y;
                v[6] = (_Float16)v1.z; v[7] = (_Float16)v1.w;
            } else {
                v = *(const half8*)&Xh[(size_t)gr * NF + c];
            }
        }
        if (ELU) {
#pragma unroll
            for (int j = 0; j < 8; j++) {
                float xv = (float)v[j];
                v[j] = (_Float16)(xv > 0.f ? xv : (expf(xv) - 1.f));
            }
        }
        *(half8*)&xs[r * 136 + c] = v;
    }
    __syncthreads();

    int w = t >> 6;              // wave id: rows w*16..w*16+15
    int lane = t & 63;
    int m = lane & 15, quad = lane >> 4;

    half8 a[4];
#pragma unroll
    for (int kc = 0; kc < 4; kc++)
        a[kc] = *(const half8*)&xs[(w * 16 + m) * 136 + kc * 32 + quad * 8];

    f32x4 acc[8];
#pragma unroll
    for (int nt = 0; nt < 8; nt++) {
        f32x4 c4 = {0.f, 0.f, 0.f, 0.f};
#pragma unroll
        for (int kc = 0; kc < 4; kc++) {
            half8 bf = *(const half8*)&WF[((nt * 4 + kc) * 64 + lane) * 8];
            c4 = __builtin_amdgcn_mfma_f32_16x16x32_f16(a[kc], bf, c4, 0, 0, 0);
        }
        acc[nt] = c4;
    }

    __syncthreads();                      // all waves done reading xs
#pragma unroll
    for (int reg = 0; reg < 4; reg++) {
        int r = w * 16 + quad * 4 + reg;
        int gr = row0 + r;
        float ds = (gr < N_NODES) ? dis[gr] : 0.f;
#pragma unroll
        for (int nt = 0; nt < 8; nt++)
            xs[r * 136 + nt * 16 + m] = (_Float16)(ds * acc[nt][reg]);
    }
    __syncthreads();
#pragma unroll
    for (int i = 0; i < 4; i++) {
        int f = i * 256 + t;
        int r = f >> 4, c = (f & 15) * 8;
        int gr = row0 + r;
        if (gr < N_NODES)
            *(half8*)&H[(size_t)gr * NF + c] = *(const half8*)&xs[r * 136 + c];
    }
}

// ------------------------------------------------------------- aggregation
// 2 nodes per wave: 32 lanes x 8 B (4 halves) per row.
// out[i] = dis[i]*(sum_src H'[src] + H'[i]) + b ; H' = dis (.) H.
// POOL (layer 2): skip the 25.6 MB Abuf write + k_pool's 25.6 MB re-read;
// reduce the block's 8 nodes in LDS and atomically add into sums.
template <bool POOL>
__global__ __launch_bounds__(256) void k_agg(const __half* __restrict__ H,
                                             const float* __restrict__ bias,
                                             const int* __restrict__ row_start,
                                             const int* __restrict__ row_end,
                                             const int* __restrict__ csr_src,
                                             const float* __restrict__ dis,
                                             const int* __restrict__ batch,
                                             void* __restrict__ outv) {
    __shared__ float pacc[NF];
    const uint2* H4 = (const uint2*)H;      // 8 B = 4 halves; row stride 32
    int t = threadIdx.x;
    int lane = t & 63;
    int node = blockIdx.x * 8 + (t >> 6) * 2 + (lane >> 5);
    int l    = lane & 31;
    int c    = l * 4;
    if (POOL) {
        if (t < NF) pacc[t] = 0.f;
        __syncthreads();
    }
    float o0 = 0.f, o1 = 0.f, o2 = 0.f, o3 = 0.f;
    bool active = node < N_NODES;
    if (active) {
        int rs = row_start[node], re = row_end[node];
        float a0 = 0.f, a1 = 0.f, a2 = 0.f, a3 = 0.f;
        int e = rs;
        for (; e + 7 < re; e += 8) {
            uint2 v[8];
#pragma unroll
            for (int j = 0; j < 8; j++) {
                int s = csr_src[e + j];
                v[j] = H4[(size_t)s * 32 + l];
            }
#pragma unroll
            for (int j = 0; j < 8; j++) {
                float2 lo = __half22float2(*(__half2*)&v[j].x);
                float2 hi = __half22float2(*(__half2*)&v[j].y);
                a0 += lo.x; a1 += lo.y; a2 += hi.x; a3 += hi.y;
            }
        }
        for (; e < re; e++) {
            int s = csr_src[e];
            uint2 v = H4[(size_t)s * 32 + l];
            float2 lo = __half22float2(*(__half2*)&v.x);
            float2 hi = __half22float2(*(__half2*)&v.y);
            a0 += lo.x; a1 += lo.y; a2 += hi.x; a3 += hi.y;
        }
        {
            uint2 v = H4[(size_t)node * 32 + l];     // self-loop term
            float2 lo = __half22float2(*(__half2*)&v.x);
            float2 hi = __half22float2(*(__half2*)&v.y);
            a0 += lo.x; a1 += lo.y; a2 += hi.x; a3 += hi.y;
        }
        float di = dis[node];
        float4 bv = *(const float4*)&bias[c];
        o0 = a0 * di + bv.x; o1 = a1 * di + bv.y;
        o2 = a2 * di + bv.z; o3 = a3 * di + bv.w;
        if (!POOL) {
            uint2 o;
            *(__half2*)&o.x = __floats2half2_rn(o0, o1);
            *(__half2*)&o.y = __floats2half2_rn(o2, o3);
            ((uint2*)outv)[(size_t)node * 32 + l] = o;
        }
    }
    if (POOL) {
        float* sums = (float*)outv;
        int first = blockIdx.x * 8;
        int last  = min(first + 7, N_NODES - 1);
        int g0 = batch[first], g7 = batch[last];
        if (active) {
            if (g0 == g7) {
                atomicAdd(&pacc[c + 0], o0);
                atomicAdd(&pacc[c + 1], o1);
                atomicAdd(&pacc[c + 2], o2);
                atomicAdd(&pacc[c + 3], o3);
            } else {                     // rare graph-boundary block
                int g = batch[node];
                atomicAdd(&sums[g * NF + c + 0], o0);
                atomicAdd(&sums[g * NF + c + 1], o1);
                atomicAdd(&sums[g * NF + c + 2], o2);
                atomicAdd(&sums[g * NF + c + 3], o3);
            }
        }
        __syncthreads();
        if (t < NF && g0 == g7) atomicAdd(&sums[g0 * NF + t], pacc[t]);
    }
}

// ---------------------------------------------------------------- heads
__global__ void k_head(const float* __restrict__ sums, const int* __restrict__ batch,
                       const float* __restrict__ wc, const float* __restrict__ bc,
                       const float* __restrict__ wr, const float* __restrict__ br,
                       float* __restrict__ out) {
    __shared__ float p[128];
    __shared__ int cnt_s;
    int g = blockIdx.x, c = threadIdx.x;
    if (c == 0) {
        int lo = 0, hi = N_NODES;
        while (lo < hi) { int m = (lo + hi) >> 1; if (batch[m] < g) lo = m + 1; else hi = m; }
        int s0 = lo;
        lo = 0; hi = N_NODES;
        while (lo < hi) { int m = (lo + hi) >> 1; if (batch[m] < g + 1) lo = m + 1; else hi = m; }
        cnt_s = lo - s0;
    }
    __syncthreads();
    float cnt = (float)max(cnt_s, 1);
    float pv = sums[g * NF + c] / cnt;
    p[c] = pv;
    out[g * NF + c] = pv;
    __syncthreads();
    if (c < N_CLASSES) {
        float d = bc[c];
        for (int k = 0; k < NF; k++) d += p[k] * wc[k * N_CLASSES + c];
        out[N_GRAPHS * NF + g * N_CLASSES + c] = d;
    }
    if (c == N_CLASSES) {
        float d = br[0];
        for (int k = 0; k < NF; k++) d += p[k] * wr[k];
        out[N_GRAPHS * NF + N_GRAPHS * N_CLASSES + g] = d;
    }
}

// ================================================================= launch
extern "C" void kernel_launch(void* const* d_in, const int* in_sizes, int n_in,
                              void* d_out, int out_size, void* d_ws, size_t ws_size,
                              hipStream_t stream) {
    const float* x     = (const float*)d_in[0];
    const int*   ei    = (const int*)d_in[1];
    const int*   batch = (const int*)d_in[2];
    const float* w0 = (const float*)d_in[3];
    const float* b0 = (const float*)d_in[4];
    const float* w1 = (const float*)d_in[5];
    const float* b1 = (const float*)d_in[6];
    const float* w2 = (const float*)d_in[7];
    const float* b2 = (const float*)d_in[8];
    const float* wc = (const float*)d_in[9];
    const float* bc = (const float*)d_in[10];
    const float* wr = (const float*)d_in[11];
    const float* br = (const float*)d_in[12];
    const int* srcp = ei;
    const int* dstp = ei + N_EDGES;
    float* out = (float*)d_out;

    char* ws = (char*)d_ws;
    size_t off = 0;
    auto alloc = [&](size_t bytes) -> void* {
        void* p = ws + off;
        off = (off + bytes + 255) & ~(size_t)255;
        return p;
    };
    int*      row_start  = (int*)alloc(N_NODES * 4);
    int*      row_end    = (int*)alloc(N_NODES * 4);
    int*      bucket_cur = (int*)alloc(NBK * 4);
    float*    dis        = (float*)alloc(N_NODES * 4);
    int*      csr_src    = (int*)alloc((size_t)NBK * SLAB * 4);   // slab layout
    __half*   Hbuf       = (__half*)alloc((size_t)N_NODES * NF * 2);
    _Float16* Ah         = (_Float16*)alloc((size_t)N_NODES * NF * 2);
    _Float16* wf         = (_Float16*)alloc((size_t)3 * NF * NF * 2);
    float*    sums       = (float*)alloc(N_GRAPHS * NF * 4);
    (void)ws_size;
    // pairs (8 MB slab) aliases Hbuf (12.8 MB): dead after k_bfill; Hbuf is
    // first written by gemm0 (stream-ordered after bfill).
    int* pairs = (int*)Hbuf;

    k_zero<<<32, 256, 0, stream>>>(bucket_cur, sums);
    k_bscatter<<<NCHUNKS, 256, 0, stream>>>(srcp, dstp, bucket_cur, pairs);
    k_bfill<<<NBK, 512, 0, stream>>>(pairs, bucket_cur, row_start, row_end, dis, csr_src);
    k_wconv<<<3, 256, 0, stream>>>(w0, w1, w2, wf);

    const int gemm_grid = (N_NODES + 63) / 64;   // 782
    const int agg_grid  = (N_NODES + 7) / 8;     // 6250 (8 nodes/block)

    // layer 0 (fp32 x read directly)
    k_gemm<false, true><<<gemm_grid, 256, 0, stream>>>(x, wf, dis, Hbuf);
    k_agg<false><<<agg_grid, 256, 0, stream>>>(Hbuf, b0, row_start, row_end, csr_src, dis, batch, Ah);
    // layer 1
    k_gemm<true, false><<<gemm_grid, 256, 0, stream>>>(Ah, wf + NF * NF, dis, Hbuf);
    k_agg<false><<<agg_grid, 256, 0, stream>>>(Hbuf, b1, row_start, row_end, csr_src, dis, batch, Ah);
    // layer 2 (pooling fused; no per-node fp32 output)
    k_gemm<true, false><<<gemm_grid, 256, 0, stream>>>(Ah, wf + 2 * NF * NF, dis, Hbuf);
    k_agg<true><<<agg_grid, 256, 0, stream>>>(Hbuf, b2, row_start, row_end, csr_src, dis, batch, sums);

    k_head<<<N_GRAPHS, 128, 0, stream>>>(sums, batch, wc, bc, wr, br, out);
}